// Round 3
// baseline (733.562 us; speedup 1.0000x reference)
//
#include <hip/hip_runtime.h>

// MEGNet-like message passing: N=10000 atoms, E=40000 edges, G=128 graphs
// ATOM=32, EDGE=32, STATE=16, D=48, STEPS=2
#define N_ATOMS 10000
#define N_EDGES 40000
#define N_GRAPH 128

// ---------------- edge GRU ----------------
// 16 edges/block, 192 threads = 2 groups x 96 channels; each thread does 8 edges
// so each We/Ue element is loaded once per block (16-edge reuse in registers).
// Epilogue fuses esum (graph segment-sum of new e) via atomics.
__global__ __launch_bounds__(192) void edge_gru_k(const float* __restrict__ a, const float* __restrict__ e,
                           const float* __restrict__ s, const int* __restrict__ pair,
                           const int* __restrict__ bgi,
                           const float* __restrict__ We, const float* __restrict__ Ue,
                           const float* __restrict__ be_in, const float* __restrict__ be_rec,
                           float* __restrict__ e_out, float* __restrict__ esum)
{
    __shared__ float xs[16][112];
    __shared__ float hs[16][32];
    __shared__ float S[16][96];
    __shared__ float Uh[16][32];
    int t = threadIdx.x;
    int ebase = blockIdx.x * 16;     // E divisible by 16

    for (int idx = t; idx < 16 * 112; idx += 192) {
        int le = idx / 112, k = idx % 112;
        int eid = ebase + le;
        int src = pair[2 * eid], dst = pair[2 * eid + 1];
        float v;
        if (k < 32)      v = a[src * 32 + k];
        else if (k < 64) v = a[dst * 32 + (k - 32)];
        else if (k < 80) v = s[bgi[eid] * 16 + (k - 64)];
        else             v = e[eid * 32 + (k - 80)];
        xs[le][k] = v;
        if (k >= 80) hs[le][k - 80] = v;
    }
    __syncthreads();

    int grp = t / 96, c = t % 96;
    int l0 = grp * 8;
    float accg[8], accu[8];
    float bi = be_in[c], br = be_rec[c];
    #pragma unroll
    for (int i = 0; i < 8; ++i) { accg[i] = bi; accu[i] = br; }
    for (int k = 0; k < 112; ++k) {
        float w = We[k * 96 + c];
        #pragma unroll
        for (int i = 0; i < 8; ++i) accg[i] += xs[l0 + i][k] * w;
    }
    #pragma unroll
    for (int k = 0; k < 32; ++k) {
        float u = Ue[k * 96 + c];
        #pragma unroll
        for (int i = 0; i < 8; ++i) accu[i] += hs[l0 + i][k] * u;
    }
    #pragma unroll
    for (int i = 0; i < 8; ++i) {
        if (c < 64) { S[l0 + i][c] = accg[i] + accu[i]; }
        else        { S[l0 + i][c] = accg[i]; Uh[l0 + i][c - 64] = accu[i]; }
    }
    __syncthreads();

    for (int idx = t; idx < 16 * 32; idx += 192) {
        int le = idx / 32, cc = idx % 32;
        int eid = ebase + le;
        float z  = 1.f / (1.f + expf(-S[le][cc]));
        float r  = 1.f / (1.f + expf(-S[le][32 + cc]));
        float hc = tanhf(S[le][64 + cc] + r * Uh[le][cc]);
        float val = z * hs[le][cc] + (1.f - z) * hc;
        e_out[eid * 32 + cc] = val;
        atomicAdd(&esum[bgi[eid] * 32 + cc], val);
    }
}

// ---------------- Y[n, c] = dot(kernel_flat[c*48 .. +48], amc[n])  (c in [0,1536)) ----------------
// amc fused: amc[n] = concat(a[n], s[agi[n]]). Also Bn[n,i] = dot(bias[i*48..+48], amc[n]).
__global__ __launch_bounds__(256) void y_k(const float* __restrict__ kernelw,
                                           const float* __restrict__ bias,
                                           const float* __restrict__ a,
                                           const float* __restrict__ s,
                                           const int* __restrict__ agi,
                                           float* __restrict__ Y, float* __restrict__ Bn)
{
    __shared__ float amcs[16][48];
    int t = threadIdx.x;
    int n0 = blockIdx.x * 16;        // N divisible by 16
    for (int idx = t; idx < 16 * 48; idx += 256) {
        int ln = idx / 48, j = idx % 48;
        int n = n0 + ln;
        amcs[ln][j] = (j < 32) ? a[n * 32 + j] : s[agi[n] * 16 + (j - 32)];
    }
    __syncthreads();

    for (int ch = 0; ch < 6; ++ch) {
        int c = ch * 256 + t;                    // 0..1535
        const float4* kr4 = reinterpret_cast<const float4*>(kernelw + (size_t)c * 48);
        float kr[48];
        #pragma unroll
        for (int q = 0; q < 12; ++q) {
            float4 v = kr4[q];
            kr[4 * q] = v.x; kr[4 * q + 1] = v.y; kr[4 * q + 2] = v.z; kr[4 * q + 3] = v.w;
        }
        #pragma unroll 4
        for (int ln = 0; ln < 16; ++ln) {
            float acc = 0.f;
            #pragma unroll
            for (int j = 0; j < 48; ++j) acc += kr[j] * amcs[ln][j];
            Y[(size_t)(n0 + ln) * 1536 + c] = acc;
        }
    }

    for (int idx = t; idx < 16 * 48; idx += 256) {
        int ln = idx / 48, i = idx % 48;
        const float* bb = bias + i * 48;
        float acc = 0.f;
        #pragma unroll
        for (int j = 0; j < 48; ++j) acc += bb[j] * amcs[ln][j];
        Bn[(n0 + ln) * 48 + i] = acc;
    }
}

// ---------------- per-edge message + scatter: agg[src] += e_new[e] . Y[dst] + Bn[dst] ----------------
// one 64-lane wave per edge, lanes 0..47 active; 4 edges per 256-thread block
__global__ __launch_bounds__(256) void edge_msg_k(const float* __restrict__ e_new,
                                                  const int* __restrict__ pair,
                                                  const float* __restrict__ Y,
                                                  const float* __restrict__ Bn,
                                                  float* __restrict__ agg)
{
    int t = threadIdx.x;
    int lane = t & 63;
    int eid = blockIdx.x * 4 + (t >> 6);
    if (eid >= N_EDGES || lane >= 48) return;
    int src = pair[2 * eid], dst = pair[2 * eid + 1];
    const float* yrow = Y + (size_t)dst * 1536 + lane;
    const float* ev = e_new + eid * 32;
    float acc = Bn[dst * 48 + lane];
    #pragma unroll 8
    for (int k = 0; k < 32; ++k) acc += ev[k] * yrow[k * 48];
    atomicAdd(&agg[src * 48 + lane], acc);
}

// ---------------- node GRU ----------------
// 16 nodes/block, 192 threads = 2 groups x 96 channels; 8 nodes per thread.
// Epilogue fuses asum (graph segment-sum of new a) via atomics.
__global__ __launch_bounds__(192) void node_gru_k(const float* __restrict__ agg, const float* __restrict__ a_in,
                           const float* __restrict__ Wn, const float* __restrict__ Un,
                           const float* __restrict__ bn_in, const float* __restrict__ bn_rec,
                           float* __restrict__ a_out, const int* __restrict__ agi,
                           float* __restrict__ asum)
{
    __shared__ float xs[16][48];
    __shared__ float hs[16][32];
    __shared__ float S[16][96];
    __shared__ float Uh[16][32];
    int t = threadIdx.x;
    int nbase = blockIdx.x * 16;     // N divisible by 16

    for (int idx = t; idx < 16 * 48; idx += 192) {
        int ln = idx / 48, k = idx % 48;
        xs[ln][k] = agg[(nbase + ln) * 48 + k];
    }
    for (int idx = t; idx < 16 * 32; idx += 192) {
        int ln = idx / 32, k = idx % 32;
        hs[ln][k] = a_in[(nbase + ln) * 32 + k];
    }
    __syncthreads();

    int grp = t / 96, c = t % 96;
    int l0 = grp * 8;
    float accg[8], accu[8];
    float bi = bn_in[c], br = bn_rec[c];
    #pragma unroll
    for (int i = 0; i < 8; ++i) { accg[i] = bi; accu[i] = br; }
    #pragma unroll 4
    for (int k = 0; k < 48; ++k) {
        float w = Wn[k * 96 + c];
        #pragma unroll
        for (int i = 0; i < 8; ++i) accg[i] += xs[l0 + i][k] * w;
    }
    #pragma unroll
    for (int k = 0; k < 32; ++k) {
        float u = Un[k * 96 + c];
        #pragma unroll
        for (int i = 0; i < 8; ++i) accu[i] += hs[l0 + i][k] * u;
    }
    #pragma unroll
    for (int i = 0; i < 8; ++i) {
        if (c < 64) { S[l0 + i][c] = accg[i] + accu[i]; }
        else        { S[l0 + i][c] = accg[i]; Uh[l0 + i][c - 64] = accu[i]; }
    }
    __syncthreads();

    for (int idx = t; idx < 16 * 32; idx += 192) {
        int ln = idx / 32, cc = idx % 32;
        int n = nbase + ln;
        float z  = 1.f / (1.f + expf(-S[ln][cc]));
        float r  = 1.f / (1.f + expf(-S[ln][32 + cc]));
        float hc = tanhf(S[ln][64 + cc] + r * Uh[ln][cc]);
        float val = z * hs[ln][cc] + (1.f - z) * hc;
        a_out[n * 32 + cc] = val;
        atomicAdd(&asum[agi[n] * 32 + cc], val);
    }
}

// ---------------- state GRU ----------------
// one graph per block, 128 threads (threads 0..79 load x, 0..47 compute)
__global__ void state_gru_k(const float* __restrict__ asum, const float* __restrict__ esum,
                            const float* __restrict__ s_in,
                            const float* __restrict__ Ws, const float* __restrict__ Us,
                            const float* __restrict__ bs_in, const float* __restrict__ bs_rec,
                            float* __restrict__ s_out)
{
    __shared__ float xs[80];
    __shared__ float hsv[16];
    __shared__ float S[48];
    __shared__ float Uh[16];
    int g = blockIdx.x;
    int t = threadIdx.x;
    if (t < 80) {
        float v;
        if (t < 32)      v = asum[g * 32 + t];
        else if (t < 64) v = esum[g * 32 + (t - 32)];
        else             v = s_in[g * 16 + (t - 64)];
        xs[t] = v;
        if (t >= 64) hsv[t - 64] = v;
    }
    __syncthreads();
    if (t < 48) {
        float gacc = bs_in[t];
        #pragma unroll
        for (int k = 0; k < 80; ++k) gacc += xs[k] * Ws[k * 48 + t];
        float u = bs_rec[t];
        #pragma unroll
        for (int k = 0; k < 16; ++k) u += hsv[k] * Us[k * 48 + t];
        if (t < 32) { S[t] = gacc + u; }
        else        { S[t] = gacc; Uh[t - 32] = u; }
    }
    __syncthreads();
    if (t < 16) {
        float z  = 1.f / (1.f + expf(-S[t]));
        float r  = 1.f / (1.f + expf(-S[16 + t]));
        float hc = tanhf(S[32 + t] + r * Uh[t]);
        s_out[g * 16 + t] = z * hsv[t] + (1.f - z) * hc;
    }
}

extern "C" void kernel_launch(void* const* d_in, const int* in_sizes, int n_in,
                              void* d_out, int out_size, void* d_ws, size_t ws_size,
                              hipStream_t stream)
{
    const float* a0      = (const float*)d_in[0];
    const float* e0      = (const float*)d_in[1];
    const float* s0      = (const float*)d_in[2];
    const int*   pair    = (const int*)d_in[3];
    const int*   agi     = (const int*)d_in[4];
    const int*   bgi     = (const int*)d_in[5];
    const float* kernelw = (const float*)d_in[6];
    const float* bias    = (const float*)d_in[7];
    const float* We      = (const float*)d_in[8];
    const float* Ue      = (const float*)d_in[9];
    const float* be_in   = (const float*)d_in[10];
    const float* be_rec  = (const float*)d_in[11];
    const float* Wn      = (const float*)d_in[12];
    const float* Un      = (const float*)d_in[13];
    const float* bn_in   = (const float*)d_in[14];
    const float* bn_rec  = (const float*)d_in[15];
    const float* Ws      = (const float*)d_in[16];
    const float* Us      = (const float*)d_in[17];
    const float* bs_in   = (const float*)d_in[18];
    const float* bs_rec  = (const float*)d_in[19];

    float* out_a = (float*)d_out;                    // N*32
    float* out_e = out_a + N_ATOMS * 32;             // E*32
    float* out_s = out_e + (size_t)N_EDGES * 32;     // G*16

    char* wp = (char*)d_ws;
    auto alloc = [&](size_t nf) { float* p = (float*)wp; wp += nf * sizeof(float); return p; };
    float* aW   = alloc((size_t)N_ATOMS * 32);
    float* eW   = alloc((size_t)N_EDGES * 32);
    float* sW   = alloc((size_t)N_GRAPH * 16);
    float* Y    = alloc((size_t)N_ATOMS * 1536);
    float* Bn   = alloc((size_t)N_ATOMS * 48);
    // agg, asum, esum contiguous -> single memset per step
    float* agg  = alloc((size_t)N_ATOMS * 48);
    float* asum = alloc((size_t)N_GRAPH * 32);
    float* esum = alloc((size_t)N_GRAPH * 32);
    size_t zero_bytes = ((size_t)N_ATOMS * 48 + N_GRAPH * 32 + N_GRAPH * 32) * sizeof(float);

    const float* a_in = a0;
    const float* e_in = e0;
    const float* s_in = s0;

    for (int step = 0; step < 2; ++step) {
        float* a_o = (step == 0) ? aW : out_a;
        float* e_o = (step == 0) ? eW : out_e;
        float* s_o = (step == 0) ? sW : out_s;

        hipMemsetAsync(agg, 0, zero_bytes, stream);
        edge_gru_k<<<N_EDGES / 16, 192, 0, stream>>>(a_in, e_in, s_in, pair, bgi,
                                                     We, Ue, be_in, be_rec, e_o, esum);
        y_k<<<N_ATOMS / 16, 256, 0, stream>>>(kernelw, bias, a_in, s_in, agi, Y, Bn);
        edge_msg_k<<<N_EDGES / 4, 256, 0, stream>>>(e_o, pair, Y, Bn, agg);
        node_gru_k<<<N_ATOMS / 16, 192, 0, stream>>>(agg, a_in, Wn, Un, bn_in, bn_rec,
                                                     a_o, agi, asum);
        state_gru_k<<<N_GRAPH, 128, 0, stream>>>(asum, esum, s_in, Ws, Us, bs_in, bs_rec, s_o);

        a_in = a_o; e_in = e_o; s_in = s_o;
    }
}

// Round 4
// 513.065 us; speedup vs baseline: 1.4298x; 1.4298x over previous
//
#include <hip/hip_runtime.h>

// MEGNet-like message passing: N=10000 atoms, E=40000 edges, G=128 graphs
// ATOM=32, EDGE=32, STATE=16, D=48, STEPS=2
#define N_ATOMS 10000
#define N_EDGES 40000
#define N_GRAPH 128

// ================= weight transpose/pack (once per launch) =================
// WTa [192][32]: c<96 -> We[k][c] (src slice), c>=96 -> We[32+k][c-96] (dst slice)
// WTs [96][16]:  We[64+k][c]
// WTee[192][32]: c<96 -> We[80+k][c], c>=96 -> Ue[k][c-96]
// WTn [96][48]:  Wn[k][c]
// WTun[96][32]:  Un[k][c]
__global__ void trans_k(const float* __restrict__ We, const float* __restrict__ Ue,
                        const float* __restrict__ Wn, const float* __restrict__ Un,
                        float* __restrict__ wta, float* __restrict__ wts,
                        float* __restrict__ wtee, float* __restrict__ wtn,
                        float* __restrict__ wtun)
{
    int idx = blockIdx.x * 256 + threadIdx.x;   // 84*256 = 21504 exact
    if (idx < 6144) {
        int c = idx / 32, k = idx % 32;
        int col = c % 96;
        int srck = (c < 96) ? k : 32 + k;
        wta[idx] = We[srck * 96 + col];
    } else if (idx < 7680) {
        int j = idx - 6144; int c = j / 16, k = j % 16;
        wts[j] = We[(64 + k) * 96 + c];
    } else if (idx < 13824) {
        int j = idx - 7680; int c = j / 32, k = j % 32;
        wtee[j] = (c < 96) ? We[(80 + k) * 96 + c] : Ue[k * 96 + (c - 96)];
    } else if (idx < 18432) {
        int j = idx - 13824; int c = j / 48, k = j % 48;
        wtn[j] = Wn[k * 96 + c];
    } else {
        int j = idx - 18432; int c = j / 32, k = j % 32;
        wtun[j] = Un[k * 96 + c];
    }
}

// ================= PA[n][c] = a[n] . WTa[c]  (c in [0,192)) =================
// 16 nodes/block, 192 threads; weight column (32 f) in regs, activations in LDS.
__global__ __launch_bounds__(192) void pa_k(const float* __restrict__ a,
                                            const float* __restrict__ wta,
                                            float* __restrict__ PA)
{
    __shared__ float as_[16][32];
    int t = threadIdx.x;
    int n0 = blockIdx.x * 16;
    if (t < 128) reinterpret_cast<float4*>(&as_[0][0])[t] =
        reinterpret_cast<const float4*>(a + (size_t)n0 * 32)[t];
    __syncthreads();

    float w[32];
    const float4* wp4 = reinterpret_cast<const float4*>(wta + t * 32);
    #pragma unroll
    for (int q = 0; q < 8; ++q) {
        float4 v = wp4[q];
        w[4*q] = v.x; w[4*q+1] = v.y; w[4*q+2] = v.z; w[4*q+3] = v.w;
    }
    float acc[16];
    #pragma unroll
    for (int i = 0; i < 16; ++i) {
        float sres = 0.f;
        #pragma unroll
        for (int k = 0; k < 32; ++k) sres += as_[i][k] * w[k];
        acc[i] = sres;
    }
    #pragma unroll
    for (int i = 0; i < 16; ++i) PA[(size_t)(n0 + i) * 192 + t] = acc[i];
}

// ================= PS[g][c] = s[g] . WTs[c] + be_in[c]  (c in [0,96)) =================
__global__ __launch_bounds__(96) void ps_k(const float* __restrict__ s,
                                           const float* __restrict__ wts,
                                           const float* __restrict__ be_in,
                                           float* __restrict__ PS)
{
    __shared__ float ss[16][16];
    int t = threadIdx.x;
    int g0 = blockIdx.x * 16;
    if (t < 64) reinterpret_cast<float4*>(&ss[0][0])[t] =
        reinterpret_cast<const float4*>(s + (size_t)g0 * 16)[t];
    __syncthreads();

    float w[16];
    const float4* wp4 = reinterpret_cast<const float4*>(wts + t * 16);
    #pragma unroll
    for (int q = 0; q < 4; ++q) {
        float4 v = wp4[q];
        w[4*q] = v.x; w[4*q+1] = v.y; w[4*q+2] = v.z; w[4*q+3] = v.w;
    }
    float b = be_in[t];
    #pragma unroll
    for (int i = 0; i < 16; ++i) {
        float sres = b;
        #pragma unroll
        for (int k = 0; k < 16; ++k) sres += ss[i][k] * w[k];
        PS[(size_t)(g0 + i) * 96 + t] = sres;
    }
}

// ================= PE[e][c] = e[e] . WTee[c] (+ be_rec for c>=96) =================
__global__ __launch_bounds__(192) void pe_k(const float* __restrict__ e,
                                            const float* __restrict__ wtee,
                                            const float* __restrict__ be_rec,
                                            float* __restrict__ PE)
{
    __shared__ float es[16][32];
    int t = threadIdx.x;
    int e0 = blockIdx.x * 16;
    if (t < 128) reinterpret_cast<float4*>(&es[0][0])[t] =
        reinterpret_cast<const float4*>(e + (size_t)e0 * 32)[t];
    __syncthreads();

    float w[32];
    const float4* wp4 = reinterpret_cast<const float4*>(wtee + t * 32);
    #pragma unroll
    for (int q = 0; q < 8; ++q) {
        float4 v = wp4[q];
        w[4*q] = v.x; w[4*q+1] = v.y; w[4*q+2] = v.z; w[4*q+3] = v.w;
    }
    float bias = (t >= 96) ? be_rec[t - 96] : 0.f;
    #pragma unroll
    for (int i = 0; i < 16; ++i) {
        float sres = bias;
        #pragma unroll
        for (int k = 0; k < 32; ++k) sres += es[i][k] * w[k];
        PE[(size_t)(e0 + i) * 192 + t] = sres;
    }
}

// ================= edge GRU gates (elementwise gather-add) =================
// 8 edges/block, 256 threads: thread = (edge, cc in [0,32))
__global__ __launch_bounds__(256) void edge_act_k(const float* __restrict__ PA,
                                                  const float* __restrict__ PS,
                                                  const float* __restrict__ PE,
                                                  const int* __restrict__ pair,
                                                  const int* __restrict__ bgi,
                                                  const float* __restrict__ e_in,
                                                  float* __restrict__ e_out,
                                                  float* __restrict__ esum)
{
    int t = threadIdx.x;
    int eid = blockIdx.x * 8 + (t >> 5);
    int cc = t & 31;
    int src = pair[2 * eid], dst = pair[2 * eid + 1], g = bgi[eid];
    const float* pas = PA + (size_t)src * 192;
    const float* pad = PA + (size_t)dst * 192 + 96;
    const float* ps  = PS + (size_t)g * 96;
    const float* pe  = PE + (size_t)eid * 192;
    float xz = pas[cc]      + pad[cc]      + ps[cc]      + pe[cc];
    float xr = pas[32 + cc] + pad[32 + cc] + ps[32 + cc] + pe[32 + cc];
    float xh = pas[64 + cc] + pad[64 + cc] + ps[64 + cc] + pe[64 + cc];
    float hz = pe[96 + cc], hr = pe[128 + cc], hh = pe[160 + cc];
    float h  = e_in[(size_t)eid * 32 + cc];
    float z  = 1.f / (1.f + expf(-(xz + hz)));
    float r  = 1.f / (1.f + expf(-(xr + hr)));
    float hc = tanhf(xh + r * hh);
    float val = z * h + (1.f - z) * hc;
    e_out[(size_t)eid * 32 + cc] = val;
    atomicAdd(&esum[g * 32 + cc], val);
}

// ================= Y[n,c] = dot(kernel_flat[c*48..+48], amc[n]); Bn likewise =================
__global__ __launch_bounds__(256) void y_k(const float* __restrict__ kernelw,
                                           const float* __restrict__ bias,
                                           const float* __restrict__ a,
                                           const float* __restrict__ s,
                                           const int* __restrict__ agi,
                                           float* __restrict__ Y, float* __restrict__ Bn)
{
    __shared__ float amcs[16][48];
    int t = threadIdx.x;
    int n0 = blockIdx.x * 16;
    for (int idx = t; idx < 16 * 48; idx += 256) {
        int ln = idx / 48, j = idx % 48;
        int n = n0 + ln;
        amcs[ln][j] = (j < 32) ? a[n * 32 + j] : s[agi[n] * 16 + (j - 32)];
    }
    __syncthreads();

    for (int ch = 0; ch < 6; ++ch) {
        int c = ch * 256 + t;
        const float4* kr4 = reinterpret_cast<const float4*>(kernelw + (size_t)c * 48);
        float kr[48];
        #pragma unroll
        for (int q = 0; q < 12; ++q) {
            float4 v = kr4[q];
            kr[4*q] = v.x; kr[4*q+1] = v.y; kr[4*q+2] = v.z; kr[4*q+3] = v.w;
        }
        #pragma unroll 4
        for (int ln = 0; ln < 16; ++ln) {
            float acc = 0.f;
            #pragma unroll
            for (int j = 0; j < 48; ++j) acc += kr[j] * amcs[ln][j];
            Y[(size_t)(n0 + ln) * 1536 + c] = acc;
        }
    }

    for (int idx = t; idx < 16 * 48; idx += 256) {
        int ln = idx / 48, i = idx % 48;
        const float* bb = bias + i * 48;
        float acc = 0.f;
        #pragma unroll
        for (int j = 0; j < 48; ++j) acc += bb[j] * amcs[ln][j];
        Bn[(n0 + ln) * 48 + i] = acc;
    }
}

// ================= per-edge message + scatter =================
__global__ __launch_bounds__(256) void edge_msg_k(const float* __restrict__ e_new,
                                                  const int* __restrict__ pair,
                                                  const float* __restrict__ Y,
                                                  const float* __restrict__ Bn,
                                                  float* __restrict__ agg)
{
    int t = threadIdx.x;
    int lane = t & 63;
    int eid = blockIdx.x * 4 + (t >> 6);
    if (eid >= N_EDGES || lane >= 48) return;
    int src = pair[2 * eid], dst = pair[2 * eid + 1];
    const float* yrow = Y + (size_t)dst * 1536 + lane;
    const float* ev = e_new + (size_t)eid * 32;
    float acc = Bn[dst * 48 + lane];
    #pragma unroll 8
    for (int k = 0; k < 32; ++k) acc += ev[k] * yrow[k * 48];
    atomicAdd(&agg[src * 48 + lane], acc);
}

// ================= PN[n][c]: c<96 agg@Wn + bn_in ; c>=96 a@Un + bn_rec =================
__global__ __launch_bounds__(192) void pn_k(const float* __restrict__ agg,
                                            const float* __restrict__ a,
                                            const float* __restrict__ wtn,
                                            const float* __restrict__ wtun,
                                            const float* __restrict__ bn_in,
                                            const float* __restrict__ bn_rec,
                                            float* __restrict__ PN)
{
    __shared__ float xs[16][48];
    __shared__ float hs[16][32];
    int t = threadIdx.x;
    int n0 = blockIdx.x * 16;
    reinterpret_cast<float4*>(&xs[0][0])[t] =
        reinterpret_cast<const float4*>(agg + (size_t)n0 * 48)[t];       // 192 float4 = 768 f
    if (t < 128) reinterpret_cast<float4*>(&hs[0][0])[t] =
        reinterpret_cast<const float4*>(a + (size_t)n0 * 32)[t];
    __syncthreads();

    float acc[16];
    if (t < 96) {
        float w[48];
        const float4* wp4 = reinterpret_cast<const float4*>(wtn + t * 48);
        #pragma unroll
        for (int q = 0; q < 12; ++q) {
            float4 v = wp4[q];
            w[4*q] = v.x; w[4*q+1] = v.y; w[4*q+2] = v.z; w[4*q+3] = v.w;
        }
        float b = bn_in[t];
        #pragma unroll
        for (int i = 0; i < 16; ++i) {
            float sres = b;
            #pragma unroll
            for (int k = 0; k < 48; ++k) sres += xs[i][k] * w[k];
            acc[i] = sres;
        }
    } else {
        float w[32];
        const float4* wp4 = reinterpret_cast<const float4*>(wtun + (t - 96) * 32);
        #pragma unroll
        for (int q = 0; q < 8; ++q) {
            float4 v = wp4[q];
            w[4*q] = v.x; w[4*q+1] = v.y; w[4*q+2] = v.z; w[4*q+3] = v.w;
        }
        float b = bn_rec[t - 96];
        #pragma unroll
        for (int i = 0; i < 16; ++i) {
            float sres = b;
            #pragma unroll
            for (int k = 0; k < 32; ++k) sres += hs[i][k] * w[k];
            acc[i] = sres;
        }
    }
    #pragma unroll
    for (int i = 0; i < 16; ++i) PN[(size_t)(n0 + i) * 192 + t] = acc[i];
}

// ================= node GRU gates (elementwise) =================
__global__ __launch_bounds__(256) void node_act_k(const float* __restrict__ PN,
                                                  const float* __restrict__ a_in,
                                                  const int* __restrict__ agi,
                                                  float* __restrict__ a_out,
                                                  float* __restrict__ asum)
{
    int t = threadIdx.x;
    int n = blockIdx.x * 8 + (t >> 5);
    int cc = t & 31;
    const float* pn = PN + (size_t)n * 192;
    float z  = 1.f / (1.f + expf(-(pn[cc] + pn[96 + cc])));
    float r  = 1.f / (1.f + expf(-(pn[32 + cc] + pn[128 + cc])));
    float hc = tanhf(pn[64 + cc] + r * pn[160 + cc]);
    float h  = a_in[(size_t)n * 32 + cc];
    float val = z * h + (1.f - z) * hc;
    a_out[(size_t)n * 32 + cc] = val;
    atomicAdd(&asum[agi[n] * 32 + cc], val);
}

// ================= state GRU =================
__global__ void state_gru_k(const float* __restrict__ asum, const float* __restrict__ esum,
                            const float* __restrict__ s_in,
                            const float* __restrict__ Ws, const float* __restrict__ Us,
                            const float* __restrict__ bs_in, const float* __restrict__ bs_rec,
                            float* __restrict__ s_out)
{
    __shared__ float xs[80];
    __shared__ float hsv[16];
    __shared__ float S[48];
    __shared__ float Uh[16];
    int g = blockIdx.x;
    int t = threadIdx.x;
    if (t < 80) {
        float v;
        if (t < 32)      v = asum[g * 32 + t];
        else if (t < 64) v = esum[g * 32 + (t - 32)];
        else             v = s_in[g * 16 + (t - 64)];
        xs[t] = v;
        if (t >= 64) hsv[t - 64] = v;
    }
    __syncthreads();
    if (t < 48) {
        float gacc = bs_in[t];
        #pragma unroll
        for (int k = 0; k < 80; ++k) gacc += xs[k] * Ws[k * 48 + t];
        float u = bs_rec[t];
        #pragma unroll
        for (int k = 0; k < 16; ++k) u += hsv[k] * Us[k * 48 + t];
        if (t < 32) { S[t] = gacc + u; }
        else        { S[t] = gacc; Uh[t - 32] = u; }
    }
    __syncthreads();
    if (t < 16) {
        float z  = 1.f / (1.f + expf(-S[t]));
        float r  = 1.f / (1.f + expf(-S[16 + t]));
        float hc = tanhf(S[32 + t] + r * Uh[t]);
        s_out[g * 16 + t] = z * hsv[t] + (1.f - z) * hc;
    }
}

extern "C" void kernel_launch(void* const* d_in, const int* in_sizes, int n_in,
                              void* d_out, int out_size, void* d_ws, size_t ws_size,
                              hipStream_t stream)
{
    const float* a0      = (const float*)d_in[0];
    const float* e0      = (const float*)d_in[1];
    const float* s0      = (const float*)d_in[2];
    const int*   pair    = (const int*)d_in[3];
    const int*   agi     = (const int*)d_in[4];
    const int*   bgi     = (const int*)d_in[5];
    const float* kernelw = (const float*)d_in[6];
    const float* bias    = (const float*)d_in[7];
    const float* We      = (const float*)d_in[8];
    const float* Ue      = (const float*)d_in[9];
    const float* be_in   = (const float*)d_in[10];
    const float* be_rec  = (const float*)d_in[11];
    const float* Wn      = (const float*)d_in[12];
    const float* Un      = (const float*)d_in[13];
    const float* bn_in   = (const float*)d_in[14];
    const float* bn_rec  = (const float*)d_in[15];
    const float* Ws      = (const float*)d_in[16];
    const float* Us      = (const float*)d_in[17];
    const float* bs_in   = (const float*)d_in[18];
    const float* bs_rec  = (const float*)d_in[19];

    float* out_a = (float*)d_out;                    // N*32
    float* out_e = out_a + N_ATOMS * 32;             // E*32
    float* out_s = out_e + (size_t)N_EDGES * 32;     // G*16

    char* wp = (char*)d_ws;
    auto alloc = [&](size_t nf) { float* p = (float*)wp; wp += nf * sizeof(float); return p; };
    float* aW   = alloc((size_t)N_ATOMS * 32);
    float* eW   = alloc((size_t)N_EDGES * 32);
    float* sW   = alloc((size_t)N_GRAPH * 16);
    float* Y    = alloc((size_t)N_ATOMS * 1536);     // 15.36M floats
    float* Bn   = alloc((size_t)N_ATOMS * 48);
    float* agg  = alloc((size_t)N_ATOMS * 48);       // agg..esum contiguous memset
    float* asum = alloc((size_t)N_GRAPH * 32);
    float* esum = alloc((size_t)N_GRAPH * 32);
    float* wta  = alloc(6144);
    float* wts  = alloc(1536);
    float* wtee = alloc(6144);
    float* wtn  = alloc(4608);
    float* wtun = alloc(3072);
    size_t zero_bytes = ((size_t)N_ATOMS * 48 + 2 * N_GRAPH * 32) * sizeof(float);

    // Alias PE/PA/PS/PN into Y (disjoint lifetimes, stream-ordered):
    //   PE,PA,PS live: pa_k..edge_act_k  (before y_k writes Y)
    //   PN lives: pn_k..node_act_k       (after edge_msg_k reads Y)
    float* PE = Y;                                       // E*192 = 7.68M floats
    float* PA = PE + (size_t)N_EDGES * 192;              // N*192 = 1.92M
    float* PS = PA + (size_t)N_ATOMS * 192;              // G*96
    float* PN = PS + (size_t)N_GRAPH * 96;               // N*192  (total 11.53M < 15.36M)

    trans_k<<<84, 256, 0, stream>>>(We, Ue, Wn, Un, wta, wts, wtee, wtn, wtun);

    const float* a_in = a0;
    const float* e_in = e0;
    const float* s_in = s0;

    for (int step = 0; step < 2; ++step) {
        float* a_o = (step == 0) ? aW : out_a;
        float* e_o = (step == 0) ? eW : out_e;
        float* s_o = (step == 0) ? sW : out_s;

        hipMemsetAsync(agg, 0, zero_bytes, stream);
        pa_k<<<N_ATOMS / 16, 192, 0, stream>>>(a_in, wta, PA);
        ps_k<<<N_GRAPH / 16, 96, 0, stream>>>(s_in, wts, be_in, PS);
        pe_k<<<N_EDGES / 16, 192, 0, stream>>>(e_in, wtee, be_rec, PE);
        edge_act_k<<<N_EDGES / 8, 256, 0, stream>>>(PA, PS, PE, pair, bgi, e_in, e_o, esum);
        y_k<<<N_ATOMS / 16, 256, 0, stream>>>(kernelw, bias, a_in, s_in, agi, Y, Bn);
        edge_msg_k<<<N_EDGES / 4, 256, 0, stream>>>(e_o, pair, Y, Bn, agg);
        pn_k<<<N_ATOMS / 16, 192, 0, stream>>>(agg, a_in, wtn, wtun, bn_in, bn_rec, PN);
        node_act_k<<<N_ATOMS / 8, 256, 0, stream>>>(PN, a_in, agi, a_o, asum);
        state_gru_k<<<N_GRAPH, 128, 0, stream>>>(asum, esum, s_in, Ws, Us, bs_in, bs_rec, s_o);

        a_in = a_o; e_in = e_o; s_in = s_o;
    }
}

// Round 8
// 447.988 us; speedup vs baseline: 1.6375x; 1.1453x over previous
//
#include <hip/hip_runtime.h>

// MEGNet-like message passing: N=10000 atoms, E=40000 edges, G=128 graphs
// ATOM=32, EDGE=32, STATE=16, D=48, STEPS=2
#define N_ATOMS 10000
#define N_EDGES 40000
#define N_GRAPH 128

typedef unsigned short ushort_t;

__device__ __forceinline__ ushort_t f2bf(float f) {
    unsigned int u = __float_as_uint(f);
    unsigned int r = (u + 0x7fffu + ((u >> 16) & 1u)) >> 16;   // RNE
    return (ushort_t)r;
}
__device__ __forceinline__ float bflo(unsigned int u) { return __uint_as_float(u << 16); }
__device__ __forceinline__ float bfhi(unsigned int u) { return __uint_as_float(u & 0xffff0000u); }

// ================= weight transpose/pack (once per launch) =================
// WTa [192][32]: c<96 -> We[k][c] (src slice), c>=96 -> We[32+k][c-96] (dst slice)
// WTs [96][16]:  We[64+k][c]
// WTee[192][32]: c<96 -> We[80+k][c], c>=96 -> Ue[k][c-96]
// WTn [96][48]:  Wn[k][c]
// WTun[96][32]:  Un[k][c]
__global__ void trans_k(const float* __restrict__ We, const float* __restrict__ Ue,
                        const float* __restrict__ Wn, const float* __restrict__ Un,
                        float* __restrict__ wta, float* __restrict__ wts,
                        float* __restrict__ wtee, float* __restrict__ wtn,
                        float* __restrict__ wtun)
{
    int idx = blockIdx.x * 256 + threadIdx.x;   // 84*256 = 21504 exact
    if (idx < 6144) {
        int c = idx / 32, k = idx % 32;
        int col = c % 96;
        int srck = (c < 96) ? k : 32 + k;
        wta[idx] = We[srck * 96 + col];
    } else if (idx < 7680) {
        int j = idx - 6144; int c = j / 16, k = j % 16;
        wts[j] = We[(64 + k) * 96 + c];
    } else if (idx < 13824) {
        int j = idx - 7680; int c = j / 32, k = j % 32;
        wtee[j] = (c < 96) ? We[(80 + k) * 96 + c] : Ue[k * 96 + (c - 96)];
    } else if (idx < 18432) {
        int j = idx - 13824; int c = j / 48, k = j % 48;
        wtn[j] = Wn[k * 96 + c];
    } else {
        int j = idx - 18432; int c = j / 32, k = j % 32;
        wtun[j] = Un[k * 96 + c];
    }
}

// ================= PA[n][c] = a[n] . WTa[c]  (c in [0,192)) =================
__global__ __launch_bounds__(192) void pa_k(const float* __restrict__ a,
                                            const float* __restrict__ wta,
                                            float* __restrict__ PA)
{
    __shared__ float as_[16][32];
    int t = threadIdx.x;
    int n0 = blockIdx.x * 16;
    if (t < 128) reinterpret_cast<float4*>(&as_[0][0])[t] =
        reinterpret_cast<const float4*>(a + (size_t)n0 * 32)[t];
    __syncthreads();

    float w[32];
    const float4* wp4 = reinterpret_cast<const float4*>(wta + t * 32);
    #pragma unroll
    for (int q = 0; q < 8; ++q) {
        float4 v = wp4[q];
        w[4*q] = v.x; w[4*q+1] = v.y; w[4*q+2] = v.z; w[4*q+3] = v.w;
    }
    #pragma unroll
    for (int i = 0; i < 16; ++i) {
        float sres = 0.f;
        #pragma unroll
        for (int k = 0; k < 32; ++k) sres += as_[i][k] * w[k];
        PA[(size_t)(n0 + i) * 192 + t] = sres;
    }
}

// ================= PS[g][c] = s[g] . WTs[c] + be_in[c]  (c in [0,96)) =================
__global__ __launch_bounds__(96) void ps_k(const float* __restrict__ s,
                                           const float* __restrict__ wts,
                                           const float* __restrict__ be_in,
                                           float* __restrict__ PS)
{
    __shared__ float ss[16][16];
    int t = threadIdx.x;
    int g0 = blockIdx.x * 16;
    if (t < 64) reinterpret_cast<float4*>(&ss[0][0])[t] =
        reinterpret_cast<const float4*>(s + (size_t)g0 * 16)[t];
    __syncthreads();

    float w[16];
    const float4* wp4 = reinterpret_cast<const float4*>(wts + t * 16);
    #pragma unroll
    for (int q = 0; q < 4; ++q) {
        float4 v = wp4[q];
        w[4*q] = v.x; w[4*q+1] = v.y; w[4*q+2] = v.z; w[4*q+3] = v.w;
    }
    float b = be_in[t];
    #pragma unroll
    for (int i = 0; i < 16; ++i) {
        float sres = b;
        #pragma unroll
        for (int k = 0; k < 16; ++k) sres += ss[i][k] * w[k];
        PS[(size_t)(g0 + i) * 96 + t] = sres;
    }
}

// ================= fused edge GRU: per-edge GEMM (S in LDS) + gates =================
// 16 edges/block, 192 threads. S[e][c]: c<96 = e@We_e ; c>=96 = e@Ue + be_rec.
__global__ __launch_bounds__(192) void edge_fused_k(const float* __restrict__ e_in,
                                                    const float* __restrict__ wtee,
                                                    const float* __restrict__ be_rec,
                                                    const float* __restrict__ PA,
                                                    const float* __restrict__ PS,
                                                    const int* __restrict__ pair,
                                                    const int* __restrict__ bgi,
                                                    float* __restrict__ e_out,
                                                    float* __restrict__ esum)
{
    __shared__ float es[16][32];
    __shared__ float S[16][192];
    int t = threadIdx.x;
    int e0b = blockIdx.x * 16;

    if (t < 128) reinterpret_cast<float4*>(&es[0][0])[t] =
        reinterpret_cast<const float4*>(e_in + (size_t)e0b * 32)[t];
    __syncthreads();

    float w[32];
    const float4* wp4 = reinterpret_cast<const float4*>(wtee + t * 32);
    #pragma unroll
    for (int q = 0; q < 8; ++q) {
        float4 v = wp4[q];
        w[4*q] = v.x; w[4*q+1] = v.y; w[4*q+2] = v.z; w[4*q+3] = v.w;
    }
    float b = (t >= 96) ? be_rec[t - 96] : 0.f;
    #pragma unroll 4
    for (int i = 0; i < 16; ++i) {
        float sres = b;
        #pragma unroll
        for (int k = 0; k < 32; ++k) sres += es[i][k] * w[k];
        S[i][t] = sres;
    }
    __syncthreads();

    for (int idx = t; idx < 512; idx += 192) {
        int le = idx >> 5, cc = idx & 31;
        int eid = e0b + le;
        int src = pair[2 * eid], dst = pair[2 * eid + 1], g = bgi[eid];
        const float* pas = PA + (size_t)src * 192;
        const float* pad = PA + (size_t)dst * 192 + 96;
        const float* ps  = PS + (size_t)g * 96;
        float xz = pas[cc]      + pad[cc]      + ps[cc]      + S[le][cc];
        float xr = pas[32 + cc] + pad[32 + cc] + ps[32 + cc] + S[le][32 + cc];
        float xh = pas[64 + cc] + pad[64 + cc] + ps[64 + cc] + S[le][64 + cc];
        float hz = S[le][96 + cc], hr = S[le][128 + cc], hh = S[le][160 + cc];
        float h  = es[le][cc];
        float z  = 1.f / (1.f + expf(-(xz + hz)));
        float r  = 1.f / (1.f + expf(-(xr + hr)));
        float hc = tanhf(xh + r * hh);
        float val = z * h + (1.f - z) * hc;
        e_out[(size_t)eid * 32 + cc] = val;
        atomicAdd(&esum[g * 32 + cc], val);
    }
}

// ================= Yp[n][i*32+k] = dot(kernel[k, i*48 .. +48], amc[n])  (bf16 out) =====
// 2 channels per thread (c0=2t, c1=2t+1 within 512-chunks); Bn stays f32.
__global__ __launch_bounds__(256) void y_k(const float* __restrict__ kernelw,
                                           const float* __restrict__ bias,
                                           const float* __restrict__ a,
                                           const float* __restrict__ s,
                                           const int* __restrict__ agi,
                                           ushort_t* __restrict__ Yb,
                                           float* __restrict__ Bn)
{
    __shared__ float amcs[16][48];
    int t = threadIdx.x;
    int n0 = blockIdx.x * 16;
    for (int idx = t; idx < 16 * 48; idx += 256) {
        int ln = idx / 48, j = idx % 48;
        int n = n0 + ln;
        amcs[ln][j] = (j < 32) ? a[n * 32 + j] : s[agi[n] * 16 + (j - 32)];
    }
    __syncthreads();

    for (int ch = 0; ch < 3; ++ch) {
        int c0 = ch * 512 + 2 * t;
        int c1 = c0 + 1;
        // c' = i*32 + k  ->  kernel_flat row offset k*2304 + i*48
        const float4* p0 = reinterpret_cast<const float4*>(kernelw + (size_t)(c0 & 31) * 2304 + (size_t)(c0 >> 5) * 48);
        const float4* p1 = reinterpret_cast<const float4*>(kernelw + (size_t)(c1 & 31) * 2304 + (size_t)(c1 >> 5) * 48);
        float kr0[48], kr1[48];
        #pragma unroll
        for (int q = 0; q < 12; ++q) {
            float4 v0 = p0[q], v1 = p1[q];
            kr0[4*q] = v0.x; kr0[4*q+1] = v0.y; kr0[4*q+2] = v0.z; kr0[4*q+3] = v0.w;
            kr1[4*q] = v1.x; kr1[4*q+1] = v1.y; kr1[4*q+2] = v1.z; kr1[4*q+3] = v1.w;
        }
        #pragma unroll 2
        for (int ln = 0; ln < 16; ++ln) {
            float s0 = 0.f, s1 = 0.f;
            #pragma unroll
            for (int j = 0; j < 48; ++j) {
                float av = amcs[ln][j];
                s0 += kr0[j] * av;
                s1 += kr1[j] * av;
            }
            ushort_t* dst = Yb + (size_t)(n0 + ln) * 1536 + c0;
            unsigned int packed = (unsigned int)f2bf(s0) | ((unsigned int)f2bf(s1) << 16);
            *reinterpret_cast<unsigned int*>(dst) = packed;
        }
    }

    for (int idx = t; idx < 16 * 48; idx += 256) {
        int ln = idx / 48, i = idx % 48;
        const float* bb = bias + i * 48;
        float acc = 0.f;
        #pragma unroll
        for (int j = 0; j < 48; ++j) acc += bb[j] * amcs[ln][j];
        Bn[(n0 + ln) * 48 + i] = acc;
    }
}

// ================= per-edge message + scatter (bf16 Y, vectorized) =================
// lane i in [0,48): reads Yp[dst][i*32 .. i*32+31] = 64 B contiguous (4x uint4)
__global__ __launch_bounds__(256) void edge_msg_k(const float* __restrict__ e_new,
                                                  const int* __restrict__ pair,
                                                  const ushort_t* __restrict__ Yb,
                                                  const float* __restrict__ Bn,
                                                  float* __restrict__ agg)
{
    int t = threadIdx.x;
    int lane = t & 63;
    int eid = blockIdx.x * 4 + (t >> 6);
    if (lane >= 48) return;
    int src = pair[2 * eid], dst = pair[2 * eid + 1];

    float ev[32];
    const float4* ep = reinterpret_cast<const float4*>(e_new + (size_t)eid * 32);
    #pragma unroll
    for (int q = 0; q < 8; ++q) {
        float4 v = ep[q];
        ev[4*q] = v.x; ev[4*q+1] = v.y; ev[4*q+2] = v.z; ev[4*q+3] = v.w;
    }

    const uint4* yp = reinterpret_cast<const uint4*>(Yb + (size_t)dst * 1536 + lane * 32);
    float acc = Bn[dst * 48 + lane];
    #pragma unroll
    for (int q = 0; q < 4; ++q) {
        uint4 v = yp[q];
        int k = q * 8;
        acc += bflo(v.x) * ev[k]     + bfhi(v.x) * ev[k + 1]
             + bflo(v.y) * ev[k + 2] + bfhi(v.y) * ev[k + 3]
             + bflo(v.z) * ev[k + 4] + bfhi(v.z) * ev[k + 5]
             + bflo(v.w) * ev[k + 6] + bfhi(v.w) * ev[k + 7];
    }
    atomicAdd(&agg[src * 48 + lane], acc);
}

// ================= fused node GRU: GEMM (S in LDS) + gates =================
// 16 nodes/block, 192 threads. S: c<96 = agg@Wn + bn_in ; c>=96 = a@Un + bn_rec.
__global__ __launch_bounds__(192) void node_fused_k(const float* __restrict__ agg,
                                                    const float* __restrict__ a_in,
                                                    const float* __restrict__ wtn,
                                                    const float* __restrict__ wtun,
                                                    const float* __restrict__ bn_in,
                                                    const float* __restrict__ bn_rec,
                                                    const int* __restrict__ agi,
                                                    float* __restrict__ a_out,
                                                    float* __restrict__ asum)
{
    __shared__ float xs[16][48];
    __shared__ float hs[16][32];
    __shared__ float S[16][192];
    int t = threadIdx.x;
    int n0 = blockIdx.x * 16;

    reinterpret_cast<float4*>(&xs[0][0])[t] =
        reinterpret_cast<const float4*>(agg + (size_t)n0 * 48)[t];       // 192 float4
    if (t < 128) reinterpret_cast<float4*>(&hs[0][0])[t] =
        reinterpret_cast<const float4*>(a_in + (size_t)n0 * 32)[t];
    __syncthreads();

    if (t < 96) {
        float w[48];
        const float4* wp4 = reinterpret_cast<const float4*>(wtn + t * 48);
        #pragma unroll
        for (int q = 0; q < 12; ++q) {
            float4 v = wp4[q];
            w[4*q] = v.x; w[4*q+1] = v.y; w[4*q+2] = v.z; w[4*q+3] = v.w;
        }
        float b = bn_in[t];
        #pragma unroll 4
        for (int i = 0; i < 16; ++i) {
            float sres = b;
            #pragma unroll
            for (int k = 0; k < 48; ++k) sres += xs[i][k] * w[k];
            S[i][t] = sres;
        }
    } else {
        float w[32];
        const float4* wp4 = reinterpret_cast<const float4*>(wtun + (t - 96) * 32);
        #pragma unroll
        for (int q = 0; q < 8; ++q) {
            float4 v = wp4[q];
            w[4*q] = v.x; w[4*q+1] = v.y; w[4*q+2] = v.z; w[4*q+3] = v.w;
        }
        float b = bn_rec[t - 96];
        #pragma unroll 4
        for (int i = 0; i < 16; ++i) {
            float sres = b;
            #pragma unroll
            for (int k = 0; k < 32; ++k) sres += hs[i][k] * w[k];
            S[i][t] = sres;
        }
    }
    __syncthreads();

    for (int idx = t; idx < 512; idx += 192) {
        int le = idx >> 5, cc = idx & 31;
        int n = n0 + le;
        float z  = 1.f / (1.f + expf(-(S[le][cc] + S[le][96 + cc])));
        float r  = 1.f / (1.f + expf(-(S[le][32 + cc] + S[le][128 + cc])));
        float hc = tanhf(S[le][64 + cc] + r * S[le][160 + cc]);
        float h  = hs[le][cc];
        float val = z * h + (1.f - z) * hc;
        a_out[(size_t)n * 32 + cc] = val;
        atomicAdd(&asum[agi[n] * 32 + cc], val);
    }
}

// ================= state GRU =================
__global__ void state_gru_k(const float* __restrict__ asum, const float* __restrict__ esum,
                            const float* __restrict__ s_in,
                            const float* __restrict__ Ws, const float* __restrict__ Us,
                            const float* __restrict__ bs_in, const float* __restrict__ bs_rec,
                            float* __restrict__ s_out)
{
    __shared__ float xs[80];
    __shared__ float hsv[16];
    __shared__ float S[48];
    __shared__ float Uh[16];
    int g = blockIdx.x;
    int t = threadIdx.x;
    if (t < 80) {
        float v;
        if (t < 32)      v = asum[g * 32 + t];
        else if (t < 64) v = esum[g * 32 + (t - 32)];
        else             v = s_in[g * 16 + (t - 64)];
        xs[t] = v;
        if (t >= 64) hsv[t - 64] = v;
    }
    __syncthreads();
    if (t < 48) {
        float gacc = bs_in[t];
        #pragma unroll
        for (int k = 0; k < 80; ++k) gacc += xs[k] * Ws[k * 48 + t];
        float u = bs_rec[t];
        #pragma unroll
        for (int k = 0; k < 16; ++k) u += hsv[k] * Us[k * 48 + t];
        if (t < 32) { S[t] = gacc + u; }
        else        { S[t] = gacc; Uh[t - 32] = u; }
    }
    __syncthreads();
    if (t < 16) {
        float z  = 1.f / (1.f + expf(-S[t]));
        float r  = 1.f / (1.f + expf(-S[16 + t]));
        float hc = tanhf(S[32 + t] + r * Uh[t]);
        s_out[g * 16 + t] = z * hsv[t] + (1.f - z) * hc;
    }
}

extern "C" void kernel_launch(void* const* d_in, const int* in_sizes, int n_in,
                              void* d_out, int out_size, void* d_ws, size_t ws_size,
                              hipStream_t stream)
{
    const float* a0      = (const float*)d_in[0];
    const float* e0      = (const float*)d_in[1];
    const float* s0      = (const float*)d_in[2];
    const int*   pair    = (const int*)d_in[3];
    const int*   agi     = (const int*)d_in[4];
    const int*   bgi     = (const int*)d_in[5];
    const float* kernelw = (const float*)d_in[6];
    const float* bias    = (const float*)d_in[7];
    const float* We      = (const float*)d_in[8];
    const float* Ue      = (const float*)d_in[9];
    const float* be_in   = (const float*)d_in[10];
    const float* be_rec  = (const float*)d_in[11];
    const float* Wn      = (const float*)d_in[12];
    const float* Un      = (const float*)d_in[13];
    const float* bn_in   = (const float*)d_in[14];
    const float* bn_rec  = (const float*)d_in[15];
    const float* Ws      = (const float*)d_in[16];
    const float* Us      = (const float*)d_in[17];
    const float* bs_in   = (const float*)d_in[18];
    const float* bs_rec  = (const float*)d_in[19];

    float* out_a = (float*)d_out;                    // N*32
    float* out_e = out_a + N_ATOMS * 32;             // E*32
    float* out_s = out_e + (size_t)N_EDGES * 32;     // G*16

    char* wp = (char*)d_ws;
    auto alloc = [&](size_t nf) { float* p = (float*)wp; wp += nf * sizeof(float); return p; };
    float* aW   = alloc((size_t)N_ATOMS * 32);
    float* eW   = alloc((size_t)N_EDGES * 32);
    float* sW   = alloc((size_t)N_GRAPH * 16);
    ushort_t* Yb = (ushort_t*)alloc((size_t)N_ATOMS * 1536 / 2);  // bf16, 30.7 MB
    float* Bn   = alloc((size_t)N_ATOMS * 48);
    float* agg  = alloc((size_t)N_ATOMS * 48);       // agg..esum contiguous memset
    float* asum = alloc((size_t)N_GRAPH * 32);
    float* esum = alloc((size_t)N_GRAPH * 32);
    float* PA   = alloc((size_t)N_ATOMS * 192);
    float* PS   = alloc((size_t)N_GRAPH * 96);
    float* wta  = alloc(6144);
    float* wts  = alloc(1536);
    float* wtee = alloc(6144);
    float* wtn  = alloc(4608);
    float* wtun = alloc(3072);
    size_t zero_bytes = ((size_t)N_ATOMS * 48 + 2 * N_GRAPH * 32) * sizeof(float);

    trans_k<<<84, 256, 0, stream>>>(We, Ue, Wn, Un, wta, wts, wtee, wtn, wtun);

    const float* a_in = a0;
    const float* e_in = e0;
    const float* s_in = s0;

    for (int step = 0; step < 2; ++step) {
        float* a_o = (step == 0) ? aW : out_a;
        float* e_o = (step == 0) ? eW : out_e;
        float* s_o = (step == 0) ? sW : out_s;

        hipMemsetAsync(agg, 0, zero_bytes, stream);
        pa_k<<<N_ATOMS / 16, 192, 0, stream>>>(a_in, wta, PA);
        ps_k<<<N_GRAPH / 16, 96, 0, stream>>>(s_in, wts, be_in, PS);
        edge_fused_k<<<N_EDGES / 16, 192, 0, stream>>>(e_in, wtee, be_rec, PA, PS,
                                                       pair, bgi, e_o, esum);
        y_k<<<N_ATOMS / 16, 256, 0, stream>>>(kernelw, bias, a_in, s_in, agi, Yb, Bn);
        edge_msg_k<<<N_EDGES / 4, 256, 0, stream>>>(e_o, pair, Yb, Bn, agg);
        node_fused_k<<<N_ATOMS / 16, 192, 0, stream>>>(agg, a_in, wtn, wtun,
                                                       bn_in, bn_rec, agi, a_o, asum);
        state_gru_k<<<N_GRAPH, 128, 0, stream>>>(asum, esum, s_in, Ws, Us, bs_in, bs_rec, s_o);

        a_in = a_o; e_in = e_o; s_in = s_o;
    }
}

// Round 10
// 378.128 us; speedup vs baseline: 1.9400x; 1.1848x over previous
//
#include <hip/hip_runtime.h>

// MEGNet-like message passing: N=10000 atoms, E=40000 edges, G=128 graphs
// ATOM=32, EDGE=32, STATE=16, D=48, STEPS=2
#define N_ATOMS 10000
#define N_EDGES 40000
#define N_GRAPH 128

typedef unsigned short ushort_t;
typedef __attribute__((ext_vector_type(8))) short bf16x8;
typedef __attribute__((ext_vector_type(4))) float f32x4;

__device__ __forceinline__ ushort_t f2bf(float f) {
    unsigned int u = __float_as_uint(f);
    unsigned int r = (u + 0x7fffu + ((u >> 16) & 1u)) >> 16;   // RNE
    return (ushort_t)r;
}
__device__ __forceinline__ float bf2f(ushort_t u) { return __uint_as_float(((unsigned int)u) << 16); }
__device__ __forceinline__ float bflo(unsigned int u) { return __uint_as_float(u << 16); }
__device__ __forceinline__ float bfhi(unsigned int u) { return __uint_as_float(u & 0xffff0000u); }

// ================= weight transpose/pack (once per launch) =================
// WTa [192][32]: c<96 -> We[k][c] (src slice), c>=96 -> We[32+k][c-96] (dst slice)
// WTs [96][16]:  We[64+k][c]
// WTee[192][32]: c<96 -> We[80+k][c], c>=96 -> Ue[k][c-96]
// WTn [96][48]:  Wn[k][c]
// WTun[96][32]:  Un[k][c]
// kb:  bf16 copy of kernel (32 x 2304)
__global__ void trans_k(const float* __restrict__ We, const float* __restrict__ Ue,
                        const float* __restrict__ Wn, const float* __restrict__ Un,
                        const float* __restrict__ kernelw,
                        float* __restrict__ wta, float* __restrict__ wts,
                        float* __restrict__ wtee, float* __restrict__ wtn,
                        float* __restrict__ wtun, ushort_t* __restrict__ kb)
{
    int idx = blockIdx.x * 256 + threadIdx.x;   // 372*256 = 95232 exact
    if (idx < 6144) {
        int c = idx / 32, k = idx % 32;
        int col = c % 96;
        int srck = (c < 96) ? k : 32 + k;
        wta[idx] = We[srck * 96 + col];
    } else if (idx < 7680) {
        int j = idx - 6144; int c = j / 16, k = j % 16;
        wts[j] = We[(64 + k) * 96 + c];
    } else if (idx < 13824) {
        int j = idx - 7680; int c = j / 32, k = j % 32;
        wtee[j] = (c < 96) ? We[(80 + k) * 96 + c] : Ue[k * 96 + (c - 96)];
    } else if (idx < 18432) {
        int j = idx - 13824; int c = j / 48, k = j % 48;
        wtn[j] = Wn[k * 96 + c];
    } else if (idx < 21504) {
        int j = idx - 18432; int c = j / 32, k = j % 32;
        wtun[j] = Un[k * 96 + c];
    } else {
        int j = idx - 21504;                    // 0 .. 73727
        kb[j] = f2bf(kernelw[j]);
    }
}

// ================= PA[n][c] = a[n] . WTa[c]  (c in [0,192)) =================
__global__ __launch_bounds__(192) void pa_k(const float* __restrict__ a,
                                            const float* __restrict__ wta,
                                            float* __restrict__ PA)
{
    __shared__ float as_[16][32];
    int t = threadIdx.x;
    int n0 = blockIdx.x * 16;
    if (t < 128) reinterpret_cast<float4*>(&as_[0][0])[t] =
        reinterpret_cast<const float4*>(a + (size_t)n0 * 32)[t];
    __syncthreads();

    float w[32];
    const float4* wp4 = reinterpret_cast<const float4*>(wta + t * 32);
    #pragma unroll
    for (int q = 0; q < 8; ++q) {
        float4 v = wp4[q];
        w[4*q] = v.x; w[4*q+1] = v.y; w[4*q+2] = v.z; w[4*q+3] = v.w;
    }
    #pragma unroll
    for (int i = 0; i < 16; ++i) {
        float sres = 0.f;
        #pragma unroll
        for (int k = 0; k < 32; ++k) sres += as_[i][k] * w[k];
        PA[(size_t)(n0 + i) * 192 + t] = sres;
    }
}

// ================= PS[g][c] = s[g] . WTs[c] + be_in[c]  (c in [0,96)) =================
__global__ __launch_bounds__(96) void ps_k(const float* __restrict__ s,
                                           const float* __restrict__ wts,
                                           const float* __restrict__ be_in,
                                           float* __restrict__ PS)
{
    __shared__ float ss[16][16];
    int t = threadIdx.x;
    int g0 = blockIdx.x * 16;
    if (t < 64) reinterpret_cast<float4*>(&ss[0][0])[t] =
        reinterpret_cast<const float4*>(s + (size_t)g0 * 16)[t];
    __syncthreads();

    float w[16];
    const float4* wp4 = reinterpret_cast<const float4*>(wts + t * 16);
    #pragma unroll
    for (int q = 0; q < 4; ++q) {
        float4 v = wp4[q];
        w[4*q] = v.x; w[4*q+1] = v.y; w[4*q+2] = v.z; w[4*q+3] = v.w;
    }
    float b = be_in[t];
    #pragma unroll
    for (int i = 0; i < 16; ++i) {
        float sres = b;
        #pragma unroll
        for (int k = 0; k < 16; ++k) sres += ss[i][k] * w[k];
        PS[(size_t)(g0 + i) * 96 + t] = sres;
    }
}

// ================= fused edge GRU: per-edge GEMM (S in LDS) + gates =================
// 16 edges/block, 192 threads. S[e][c]: c<96 = e@We_e ; c>=96 = e@Ue + be_rec.
__global__ __launch_bounds__(192) void edge_fused_k(const float* __restrict__ e_in,
                                                    const float* __restrict__ wtee,
                                                    const float* __restrict__ be_rec,
                                                    const float* __restrict__ PA,
                                                    const float* __restrict__ PS,
                                                    const int* __restrict__ pair,
                                                    const int* __restrict__ bgi,
                                                    float* __restrict__ e_out,
                                                    float* __restrict__ esum)
{
    __shared__ float es[16][32];
    __shared__ float S[16][192];
    int t = threadIdx.x;
    int e0b = blockIdx.x * 16;

    if (t < 128) reinterpret_cast<float4*>(&es[0][0])[t] =
        reinterpret_cast<const float4*>(e_in + (size_t)e0b * 32)[t];
    __syncthreads();

    float w[32];
    const float4* wp4 = reinterpret_cast<const float4*>(wtee + t * 32);
    #pragma unroll
    for (int q = 0; q < 8; ++q) {
        float4 v = wp4[q];
        w[4*q] = v.x; w[4*q+1] = v.y; w[4*q+2] = v.z; w[4*q+3] = v.w;
    }
    float b = (t >= 96) ? be_rec[t - 96] : 0.f;
    #pragma unroll 4
    for (int i = 0; i < 16; ++i) {
        float sres = b;
        #pragma unroll
        for (int k = 0; k < 32; ++k) sres += es[i][k] * w[k];
        S[i][t] = sres;
    }
    __syncthreads();

    for (int idx = t; idx < 512; idx += 192) {
        int le = idx >> 5, cc = idx & 31;
        int eid = e0b + le;
        int src = pair[2 * eid], dst = pair[2 * eid + 1], g = bgi[eid];
        const float* pas = PA + (size_t)src * 192;
        const float* pad = PA + (size_t)dst * 192 + 96;
        const float* ps  = PS + (size_t)g * 96;
        float xz = pas[cc]      + pad[cc]      + ps[cc]      + S[le][cc];
        float xr = pas[32 + cc] + pad[32 + cc] + ps[32 + cc] + S[le][32 + cc];
        float xh = pas[64 + cc] + pad[64 + cc] + ps[64 + cc] + S[le][64 + cc];
        float hz = S[le][96 + cc], hr = S[le][128 + cc], hh = S[le][160 + cc];
        float h  = es[le][cc];
        float z  = 1.f / (1.f + expf(-(xz + hz)));
        float r  = 1.f / (1.f + expf(-(xr + hr)));
        float hc = tanhf(xh + r * hh);
        float val = z * h + (1.f - z) * hc;
        e_out[(size_t)eid * 32 + cc] = val;
        atomicAdd(&esum[g * 32 + cc], val);
    }
}

// ================= Y via MFMA: Yp[n][i*32+kk] = dot(kernel[kk, i*48..+48], amc[n]) =====
// 32 nodes/block (2 M-tiles), 256 threads = 4 waves; wave w handles N-tiles w, w+4, ...
// A: amc bf16 in LDS padded [32][64]; B: kb bf16, frag = one uint4.
// mfma_f32_16x16x32_bf16: C/D col=lane&15, row=(lane>>4)*4+reg (HW-verified).
// A/B packed with identical j-ordering -> internal k-permutation cancels.
__global__ __launch_bounds__(256) void y_mfma_k(const ushort_t* __restrict__ kb,
                                                const float* __restrict__ bias,
                                                const float* __restrict__ a,
                                                const float* __restrict__ s,
                                                const int* __restrict__ agi,
                                                ushort_t* __restrict__ Yb,
                                                float* __restrict__ Bn)
{
    __shared__ ushort_t amcs[32][64];
    int t = threadIdx.x;
    int n0 = blockIdx.x * 32;

    for (int idx = t; idx < 32 * 64; idx += 256) {
        int row = idx >> 6, j = idx & 63;
        int n = n0 + row;
        float v = 0.f;
        if (n < N_ATOMS) {
            if (j < 32)      v = a[(size_t)n * 32 + j];
            else if (j < 48) v = s[agi[n] * 16 + (j - 32)];
        }
        amcs[row][j] = f2bf(v);
    }
    __syncthreads();

    int lane = t & 63;
    int wv = t >> 6;
    int cl = lane & 15;
    int g  = lane >> 4;

    bf16x8 zero8 = {0, 0, 0, 0, 0, 0, 0, 0};

    bf16x8 A[2][2];
    #pragma unroll
    for (int mt = 0; mt < 2; ++mt) {
        #pragma unroll
        for (int kh = 0; kh < 2; ++kh) {
            A[mt][kh] = *reinterpret_cast<const bf16x8*>(&amcs[mt * 16 + cl][kh * 32 + g * 8]);
        }
    }

    for (int nt = wv; nt < 96; nt += 4) {
        int c = nt * 16 + cl;
        int kk = c & 31, ii = c >> 5;
        const ushort_t* kbase = kb + (size_t)kk * 2304 + ii * 48;
        bf16x8 B0 = *reinterpret_cast<const bf16x8*>(kbase + g * 8);
        bf16x8 B1 = (g < 2) ? *reinterpret_cast<const bf16x8*>(kbase + 32 + g * 8) : zero8;
        #pragma unroll
        for (int mt = 0; mt < 2; ++mt) {
            f32x4 acc = {0.f, 0.f, 0.f, 0.f};
            acc = __builtin_amdgcn_mfma_f32_16x16x32_bf16(A[mt][0], B0, acc, 0, 0, 0);
            acc = __builtin_amdgcn_mfma_f32_16x16x32_bf16(A[mt][1], B1, acc, 0, 0, 0);
            #pragma unroll
            for (int r = 0; r < 4; ++r) {
                int n = n0 + mt * 16 + g * 4 + r;
                if (n < N_ATOMS) Yb[(size_t)n * 1536 + c] = f2bf(acc[r]);
            }
        }
    }

    // Bn[n][i] = dot(bias[i*48..+48], amc[n])  (bf16 amc, f32 bias/accum)
    for (int idx = t; idx < 32 * 48; idx += 256) {
        int row = idx / 48, i = idx % 48;
        int n = n0 + row;
        if (n >= N_ATOMS) continue;
        const float* bb = bias + i * 48;
        float accv = 0.f;
        #pragma unroll
        for (int j = 0; j < 48; ++j) accv += bb[j] * bf2f(amcs[row][j]);
        Bn[(size_t)n * 48 + i] = accv;
    }
}

// ================= per-edge message + scatter (bf16 Y, vectorized) =================
// lane i in [0,48): reads Yp[dst][i*32 .. i*32+31] = 64 B contiguous (4x uint4)
__global__ __launch_bounds__(256) void edge_msg_k(const float* __restrict__ e_new,
                                                  const int* __restrict__ pair,
                                                  const ushort_t* __restrict__ Yb,
                                                  const float* __restrict__ Bn,
                                                  float* __restrict__ agg)
{
    int t = threadIdx.x;
    int lane = t & 63;
    int eid = blockIdx.x * 4 + (t >> 6);
    if (lane >= 48) return;
    int src = pair[2 * eid], dst = pair[2 * eid + 1];

    float ev[32];
    const float4* ep = reinterpret_cast<const float4*>(e_new + (size_t)eid * 32);
    #pragma unroll
    for (int q = 0; q < 8; ++q) {
        float4 v = ep[q];
        ev[4*q] = v.x; ev[4*q+1] = v.y; ev[4*q+2] = v.z; ev[4*q+3] = v.w;
    }

    const uint4* yp = reinterpret_cast<const uint4*>(Yb + (size_t)dst * 1536 + lane * 32);
    float acc = Bn[dst * 48 + lane];
    #pragma unroll
    for (int q = 0; q < 4; ++q) {
        uint4 v = yp[q];
        int k = q * 8;
        acc += bflo(v.x) * ev[k]     + bfhi(v.x) * ev[k + 1]
             + bflo(v.y) * ev[k + 2] + bfhi(v.y) * ev[k + 3]
             + bflo(v.z) * ev[k + 4] + bfhi(v.z) * ev[k + 5]
             + bflo(v.w) * ev[k + 6] + bfhi(v.w) * ev[k + 7];
    }
    atomicAdd(&agg[src * 48 + lane], acc);
}

// ================= fused node GRU: GEMM (S in LDS) + gates =================
// 16 nodes/block, 192 threads. S: c<96 = agg@Wn + bn_in ; c>=96 = a@Un + bn_rec.
__global__ __launch_bounds__(192) void node_fused_k(const float* __restrict__ agg,
                                                    const float* __restrict__ a_in,
                                                    const float* __restrict__ wtn,
                                                    const float* __restrict__ wtun,
                                                    const float* __restrict__ bn_in,
                                                    const float* __restrict__ bn_rec,
                                                    const int* __restrict__ agi,
                                                    float* __restrict__ a_out,
                                                    float* __restrict__ asum)
{
    __shared__ float xs[16][48];
    __shared__ float hs[16][32];
    __shared__ float S[16][192];
    int t = threadIdx.x;
    int n0 = blockIdx.x * 16;

    reinterpret_cast<float4*>(&xs[0][0])[t] =
        reinterpret_cast<const float4*>(agg + (size_t)n0 * 48)[t];       // 192 float4
    if (t < 128) reinterpret_cast<float4*>(&hs[0][0])[t] =
        reinterpret_cast<const float4*>(a_in + (size_t)n0 * 32)[t];
    __syncthreads();

    if (t < 96) {
        float w[48];
        const float4* wp4 = reinterpret_cast<const float4*>(wtn + t * 48);
        #pragma unroll
        for (int q = 0; q < 12; ++q) {
            float4 v = wp4[q];
            w[4*q] = v.x; w[4*q+1] = v.y; w[4*q+2] = v.z; w[4*q+3] = v.w;
        }
        float b = bn_in[t];
        #pragma unroll 4
        for (int i = 0; i < 16; ++i) {
            float sres = b;
            #pragma unroll
            for (int k = 0; k < 48; ++k) sres += xs[i][k] * w[k];
            S[i][t] = sres;
        }
    } else {
        float w[32];
        const float4* wp4 = reinterpret_cast<const float4*>(wtun + (t - 96) * 32);
        #pragma unroll
        for (int q = 0; q < 8; ++q) {
            float4 v = wp4[q];
            w[4*q] = v.x; w[4*q+1] = v.y; w[4*q+2] = v.z; w[4*q+3] = v.w;
        }
        float b = bn_rec[t - 96];
        #pragma unroll 4
        for (int i = 0; i < 16; ++i) {
            float sres = b;
            #pragma unroll
            for (int k = 0; k < 32; ++k) sres += hs[i][k] * w[k];
            S[i][t] = sres;
        }
    }
    __syncthreads();

    for (int idx = t; idx < 512; idx += 192) {
        int le = idx >> 5, cc = idx & 31;
        int n = n0 + le;
        float z  = 1.f / (1.f + expf(-(S[le][cc] + S[le][96 + cc])));
        float r  = 1.f / (1.f + expf(-(S[le][32 + cc] + S[le][128 + cc])));
        float hc = tanhf(S[le][64 + cc] + r * S[le][160 + cc]);
        float h  = hs[le][cc];
        float val = z * h + (1.f - z) * hc;
        a_out[(size_t)n * 32 + cc] = val;
        atomicAdd(&asum[agi[n] * 32 + cc], val);
    }
}

// ================= state GRU =================
__global__ void state_gru_k(const float* __restrict__ asum, const float* __restrict__ esum,
                            const float* __restrict__ s_in,
                            const float* __restrict__ Ws, const float* __restrict__ Us,
                            const float* __restrict__ bs_in, const float* __restrict__ bs_rec,
                            float* __restrict__ s_out)
{
    __shared__ float xs[80];
    __shared__ float hsv[16];
    __shared__ float S[48];
    __shared__ float Uh[16];
    int g = blockIdx.x;
    int t = threadIdx.x;
    if (t < 80) {
        float v;
        if (t < 32)      v = asum[g * 32 + t];
        else if (t < 64) v = esum[g * 32 + (t - 32)];
        else             v = s_in[g * 16 + (t - 64)];
        xs[t] = v;
        if (t >= 64) hsv[t - 64] = v;
    }
    __syncthreads();
    if (t < 48) {
        float gacc = bs_in[t];
        #pragma unroll
        for (int k = 0; k < 80; ++k) gacc += xs[k] * Ws[k * 48 + t];
        float u = bs_rec[t];
        #pragma unroll
        for (int k = 0; k < 16; ++k) u += hsv[k] * Us[k * 48 + t];
        if (t < 32) { S[t] = gacc + u; }
        else        { S[t] = gacc; Uh[t - 32] = u; }
    }
    __syncthreads();
    if (t < 16) {
        float z  = 1.f / (1.f + expf(-S[t]));
        float r  = 1.f / (1.f + expf(-S[16 + t]));
        float hc = tanhf(S[32 + t] + r * Uh[t]);
        s_out[g * 16 + t] = z * hsv[t] + (1.f - z) * hc;
    }
}

extern "C" void kernel_launch(void* const* d_in, const int* in_sizes, int n_in,
                              void* d_out, int out_size, void* d_ws, size_t ws_size,
                              hipStream_t stream)
{
    const float* a0      = (const float*)d_in[0];
    const float* e0      = (const float*)d_in[1];
    const float* s0      = (const float*)d_in[2];
    const int*   pair    = (const int*)d_in[3];
    const int*   agi     = (const int*)d_in[4];
    const int*   bgi     = (const int*)d_in[5];
    const float* kernelw = (const float*)d_in[6];
    const float* bias    = (const float*)d_in[7];
    const float* We      = (const float*)d_in[8];
    const float* Ue      = (const float*)d_in[9];
    const float* be_in   = (const float*)d_in[10];
    const float* be_rec  = (const float*)d_in[11];
    const float* Wn      = (const float*)d_in[12];
    const float* Un      = (const float*)d_in[13];
    const float* bn_in   = (const float*)d_in[14];
    const float* bn_rec  = (const float*)d_in[15];
    const float* Ws      = (const float*)d_in[16];
    const float* Us      = (const float*)d_in[17];
    const float* bs_in   = (const float*)d_in[18];
    const float* bs_rec  = (const float*)d_in[19];

    float* out_a = (float*)d_out;                    // N*32
    float* out_e = out_a + N_ATOMS * 32;             // E*32
    float* out_s = out_e + (size_t)N_EDGES * 32;     // G*16

    char* wp = (char*)d_ws;
    auto alloc = [&](size_t nf) { float* p = (float*)wp; wp += nf * sizeof(float); return p; };
    float* aW   = alloc((size_t)N_ATOMS * 32);
    float* eW   = alloc((size_t)N_EDGES * 32);
    float* sW   = alloc((size_t)N_GRAPH * 16);
    ushort_t* Yb = (ushort_t*)alloc((size_t)N_ATOMS * 1536 / 2);  // bf16, 30.7 MB
    float* Bn   = alloc((size_t)N_ATOMS * 48);
    float* agg  = alloc((size_t)N_ATOMS * 48);       // agg..esum contiguous memset
    float* asum = alloc((size_t)N_GRAPH * 32);
    float* esum = alloc((size_t)N_GRAPH * 32);
    float* PA   = alloc((size_t)N_ATOMS * 192);
    float* PS   = alloc((size_t)N_GRAPH * 96);
    float* wta  = alloc(6144);
    float* wts  = alloc(1536);
    float* wtee = alloc(6144);
    float* wtn  = alloc(4608);
    float* wtun = alloc(3072);
    ushort_t* kb = (ushort_t*)alloc(36864);          // 73728 bf16 = kernel(32x2304)
    size_t zero_bytes = ((size_t)N_ATOMS * 48 + 2 * N_GRAPH * 32) * sizeof(float);

    trans_k<<<372, 256, 0, stream>>>(We, Ue, Wn, Un, kernelw,
                                     wta, wts, wtee, wtn, wtun, kb);

    const float* a_in = a0;
    const float* e_in = e0;
    const float* s_in = s0;

    for (int step = 0; step < 2; ++step) {
        float* a_o = (step == 0) ? aW : out_a;
        float* e_o = (step == 0) ? eW : out_e;
        float* s_o = (step == 0) ? sW : out_s;

        hipMemsetAsync(agg, 0, zero_bytes, stream);
        pa_k<<<N_ATOMS / 16, 192, 0, stream>>>(a_in, wta, PA);
        ps_k<<<N_GRAPH / 16, 96, 0, stream>>>(s_in, wts, be_in, PS);
        edge_fused_k<<<N_EDGES / 16, 192, 0, stream>>>(e_in, wtee, be_rec, PA, PS,
                                                       pair, bgi, e_o, esum);
        y_mfma_k<<<(N_ATOMS + 31) / 32, 256, 0, stream>>>(kb, bias, a_in, s_in, agi, Yb, Bn);
        edge_msg_k<<<N_EDGES / 4, 256, 0, stream>>>(e_o, pair, Yb, Bn, agg);
        node_fused_k<<<N_ATOMS / 16, 192, 0, stream>>>(agg, a_in, wtn, wtun,
                                                       bn_in, bn_rec, agi, a_o, asum);
        state_gru_k<<<N_GRAPH, 128, 0, stream>>>(asum, esum, s_in, Ws, Us, bs_in, bs_rec, s_o);

        a_in = a_o; e_in = e_o; s_in = s_o;
    }
}

// Round 13
// 311.334 us; speedup vs baseline: 2.3562x; 1.2145x over previous
//
#include <hip/hip_runtime.h>

// MEGNet-like message passing: N=10000 atoms, E=40000 edges, G=128 graphs
// ATOM=32, EDGE=32, STATE=16, D=48, STEPS=2
#define N_ATOMS 10000
#define N_EDGES 40000
#define N_GRAPH 128

typedef unsigned short ushort_t;
typedef __attribute__((ext_vector_type(8))) short bf16x8;
typedef __attribute__((ext_vector_type(4))) float f32x4;

__device__ __forceinline__ ushort_t f2bf(float f) {
    unsigned int u = __float_as_uint(f);
    unsigned int r = (u + 0x7fffu + ((u >> 16) & 1u)) >> 16;   // RNE
    return (ushort_t)r;
}
__device__ __forceinline__ float bf2f(ushort_t u) { return __uint_as_float(((unsigned int)u) << 16); }
__device__ __forceinline__ float bflo(unsigned int u) { return __uint_as_float(u << 16); }
__device__ __forceinline__ float bfhi(unsigned int u) { return __uint_as_float(u & 0xffff0000u); }

// ================= weight transpose/pack (once per launch) =================
__global__ void trans_k(const float* __restrict__ We, const float* __restrict__ Ue,
                        const float* __restrict__ Wn, const float* __restrict__ Un,
                        const float* __restrict__ kernelw,
                        float* __restrict__ wta, float* __restrict__ wts,
                        float* __restrict__ wtee, float* __restrict__ wtn,
                        float* __restrict__ wtun, ushort_t* __restrict__ kb)
{
    int idx = blockIdx.x * 256 + threadIdx.x;   // 372*256 = 95232 exact
    if (idx < 6144) {
        int c = idx / 32, k = idx % 32;
        int col = c % 96;
        int srck = (c < 96) ? k : 32 + k;
        wta[idx] = We[srck * 96 + col];
    } else if (idx < 7680) {
        int j = idx - 6144; int c = j / 16, k = j % 16;
        wts[j] = We[(64 + k) * 96 + c];
    } else if (idx < 13824) {
        int j = idx - 7680; int c = j / 32, k = j % 32;
        wtee[j] = (c < 96) ? We[(80 + k) * 96 + c] : Ue[k * 96 + (c - 96)];
    } else if (idx < 18432) {
        int j = idx - 13824; int c = j / 48, k = j % 48;
        wtn[j] = Wn[k * 96 + c];
    } else if (idx < 21504) {
        int j = idx - 18432; int c = j / 32, k = j % 32;
        wtun[j] = Un[k * 96 + c];
    } else {
        int j = idx - 21504;                    // 0 .. 73727
        kb[j] = f2bf(kernelw[j]);
    }
}

// ================= PA[n][c] = a[n] . WTa[c]  (c in [0,192)) =================
__global__ __launch_bounds__(192) void pa_k(const float* __restrict__ a,
                                            const float* __restrict__ wta,
                                            float* __restrict__ PA)
{
    __shared__ float as_[16][32];
    int t = threadIdx.x;
    int n0 = blockIdx.x * 16;
    if (t < 128) reinterpret_cast<float4*>(&as_[0][0])[t] =
        reinterpret_cast<const float4*>(a + (size_t)n0 * 32)[t];
    __syncthreads();

    float w[32];
    const float4* wp4 = reinterpret_cast<const float4*>(wta + t * 32);
    #pragma unroll
    for (int q = 0; q < 8; ++q) {
        float4 v = wp4[q];
        w[4*q] = v.x; w[4*q+1] = v.y; w[4*q+2] = v.z; w[4*q+3] = v.w;
    }
    #pragma unroll
    for (int i = 0; i < 16; ++i) {
        float sres = 0.f;
        #pragma unroll
        for (int k = 0; k < 32; ++k) sres += as_[i][k] * w[k];
        PA[(size_t)(n0 + i) * 192 + t] = sres;
    }
}

// ================= PS[g][c] = s[g] . WTs[c] + be_in[c]  (c in [0,96)) =================
__global__ __launch_bounds__(96) void ps_k(const float* __restrict__ s,
                                           const float* __restrict__ wts,
                                           const float* __restrict__ be_in,
                                           float* __restrict__ PS)
{
    __shared__ float ss[16][16];
    int t = threadIdx.x;
    int g0 = blockIdx.x * 16;
    if (t < 64) reinterpret_cast<float4*>(&ss[0][0])[t] =
        reinterpret_cast<const float4*>(s + (size_t)g0 * 16)[t];
    __syncthreads();

    float w[16];
    const float4* wp4 = reinterpret_cast<const float4*>(wts + t * 16);
    #pragma unroll
    for (int q = 0; q < 4; ++q) {
        float4 v = wp4[q];
        w[4*q] = v.x; w[4*q+1] = v.y; w[4*q+2] = v.z; w[4*q+3] = v.w;
    }
    float b = be_in[t];
    #pragma unroll
    for (int i = 0; i < 16; ++i) {
        float sres = b;
        #pragma unroll
        for (int k = 0; k < 16; ++k) sres += ss[i][k] * w[k];
        PS[(size_t)(g0 + i) * 96 + t] = sres;
    }
}

// ================= fused edge GRU: per-edge GEMM (S in LDS) + gates =================
// 16 edges/block, 192 threads. S[e][c]: c<96 = e@We_e ; c>=96 = e@Ue + be_rec.
// esum: per-block LDS pre-reduction (bgi sorted -> ~1 graph/block), then <=few atomics.
__global__ __launch_bounds__(192) void edge_fused_k(const float* __restrict__ e_in,
                                                    const float* __restrict__ wtee,
                                                    const float* __restrict__ be_rec,
                                                    const float* __restrict__ PA,
                                                    const float* __restrict__ PS,
                                                    const int* __restrict__ pair,
                                                    const int* __restrict__ bgi,
                                                    float* __restrict__ e_out,
                                                    float* __restrict__ esum)
{
    __shared__ float es[16][32];
    __shared__ float S[16][192];
    __shared__ int garr[16];
    int t = threadIdx.x;
    int e0b = blockIdx.x * 16;

    if (t < 128) reinterpret_cast<float4*>(&es[0][0])[t] =
        reinterpret_cast<const float4*>(e_in + (size_t)e0b * 32)[t];
    if (t >= 128 && t < 144) garr[t - 128] = bgi[e0b + (t - 128)];
    __syncthreads();

    float w[32];
    const float4* wp4 = reinterpret_cast<const float4*>(wtee + t * 32);
    #pragma unroll
    for (int q = 0; q < 8; ++q) {
        float4 v = wp4[q];
        w[4*q] = v.x; w[4*q+1] = v.y; w[4*q+2] = v.z; w[4*q+3] = v.w;
    }
    float b = (t >= 96) ? be_rec[t - 96] : 0.f;
    #pragma unroll 4
    for (int i = 0; i < 16; ++i) {
        float sres = b;
        #pragma unroll
        for (int k = 0; k < 32; ++k) sres += es[i][k] * w[k];
        S[i][t] = sres;
    }
    __syncthreads();

    for (int idx = t; idx < 512; idx += 192) {
        int le = idx >> 5, cc = idx & 31;
        int eid = e0b + le;
        int src = pair[2 * eid], dst = pair[2 * eid + 1];
        const float* pas = PA + (size_t)src * 192;
        const float* pad = PA + (size_t)dst * 192 + 96;
        const float* ps  = PS + (size_t)garr[le] * 96;
        float xz = pas[cc]      + pad[cc]      + ps[cc]      + S[le][cc];
        float xr = pas[32 + cc] + pad[32 + cc] + ps[32 + cc] + S[le][32 + cc];
        float xh = pas[64 + cc] + pad[64 + cc] + ps[64 + cc] + S[le][64 + cc];
        float hz = S[le][96 + cc], hr = S[le][128 + cc], hh = S[le][160 + cc];
        float h  = es[le][cc];
        float z  = 1.f / (1.f + expf(-(xz + hz)));
        float r  = 1.f / (1.f + expf(-(xr + hr)));
        float hc = tanhf(xh + r * hh);
        float val = z * h + (1.f - z) * hc;
        e_out[(size_t)eid * 32 + cc] = val;
        es[le][cc] = val;                       // stash for block-level esum reduction
    }
    __syncthreads();

    // per-block segment reduction over sorted bgi, then one atomic per (segment, channel)
    if (t < 32) {
        int cc = t;
        int gprev = garr[0];
        float run = 0.f;
        #pragma unroll 4
        for (int le = 0; le < 16; ++le) {
            int gcur = garr[le];                // wave-uniform
            if (gcur != gprev) {
                atomicAdd(&esum[gprev * 32 + cc], run);
                run = 0.f; gprev = gcur;
            }
            run += es[le][cc];
        }
        atomicAdd(&esum[gprev * 32 + cc], run);
    }
}

// ================= Y via MFMA: Yp[n][i*32+kk] = dot(kernel[kk, i*48..+48], amc[n]) =====
__global__ __launch_bounds__(256) void y_mfma_k(const ushort_t* __restrict__ kb,
                                                const float* __restrict__ bias,
                                                const float* __restrict__ a,
                                                const float* __restrict__ s,
                                                const int* __restrict__ agi,
                                                ushort_t* __restrict__ Yb,
                                                float* __restrict__ Bn)
{
    __shared__ ushort_t amcs[32][64];
    int t = threadIdx.x;
    int n0 = blockIdx.x * 32;

    for (int idx = t; idx < 32 * 64; idx += 256) {
        int row = idx >> 6, j = idx & 63;
        int n = n0 + row;
        float v = 0.f;
        if (n < N_ATOMS) {
            if (j < 32)      v = a[(size_t)n * 32 + j];
            else if (j < 48) v = s[agi[n] * 16 + (j - 32)];
        }
        amcs[row][j] = f2bf(v);
    }
    __syncthreads();

    int lane = t & 63;
    int wv = t >> 6;
    int cl = lane & 15;
    int g  = lane >> 4;

    bf16x8 zero8 = {0, 0, 0, 0, 0, 0, 0, 0};

    bf16x8 A[2][2];
    #pragma unroll
    for (int mt = 0; mt < 2; ++mt) {
        #pragma unroll
        for (int kh = 0; kh < 2; ++kh) {
            A[mt][kh] = *reinterpret_cast<const bf16x8*>(&amcs[mt * 16 + cl][kh * 32 + g * 8]);
        }
    }

    for (int nt = wv; nt < 96; nt += 4) {
        int c = nt * 16 + cl;
        int kk = c & 31, ii = c >> 5;
        const ushort_t* kbase = kb + (size_t)kk * 2304 + ii * 48;
        bf16x8 B0 = *reinterpret_cast<const bf16x8*>(kbase + g * 8);
        bf16x8 B1 = (g < 2) ? *reinterpret_cast<const bf16x8*>(kbase + 32 + g * 8) : zero8;
        #pragma unroll
        for (int mt = 0; mt < 2; ++mt) {
            f32x4 acc = {0.f, 0.f, 0.f, 0.f};
            acc = __builtin_amdgcn_mfma_f32_16x16x32_bf16(A[mt][0], B0, acc, 0, 0, 0);
            acc = __builtin_amdgcn_mfma_f32_16x16x32_bf16(A[mt][1], B1, acc, 0, 0, 0);
            #pragma unroll
            for (int r = 0; r < 4; ++r) {
                int n = n0 + mt * 16 + g * 4 + r;
                if (n < N_ATOMS) Yb[(size_t)n * 1536 + c] = f2bf(acc[r]);
            }
        }
    }

    // Bn[n][i] = dot(bias[i*48..+48], amc[n])  (bf16 amc, f32 bias/accum)
    for (int idx = t; idx < 32 * 48; idx += 256) {
        int row = idx / 48, i = idx % 48;
        int n = n0 + row;
        if (n >= N_ATOMS) continue;
        const float* bb = bias + i * 48;
        float accv = 0.f;
        #pragma unroll
        for (int j = 0; j < 48; ++j) accv += bb[j] * bf2f(amcs[row][j]);
        Bn[(size_t)n * 48 + i] = accv;
    }
}

// ================= per-edge message + scatter (bf16 Y, vectorized) =================
__global__ __launch_bounds__(256) void edge_msg_k(const float* __restrict__ e_new,
                                                  const int* __restrict__ pair,
                                                  const ushort_t* __restrict__ Yb,
                                                  const float* __restrict__ Bn,
                                                  float* __restrict__ agg)
{
    int t = threadIdx.x;
    int lane = t & 63;
    int eid = blockIdx.x * 4 + (t >> 6);
    if (lane >= 48) return;
    int src = pair[2 * eid], dst = pair[2 * eid + 1];

    float ev[32];
    const float4* ep = reinterpret_cast<const float4*>(e_new + (size_t)eid * 32);
    #pragma unroll
    for (int q = 0; q < 8; ++q) {
        float4 v = ep[q];
        ev[4*q] = v.x; ev[4*q+1] = v.y; ev[4*q+2] = v.z; ev[4*q+3] = v.w;
    }

    const uint4* yp = reinterpret_cast<const uint4*>(Yb + (size_t)dst * 1536 + lane * 32);
    float acc = Bn[dst * 48 + lane];
    #pragma unroll
    for (int q = 0; q < 4; ++q) {
        uint4 v = yp[q];
        int k = q * 8;
        acc += bflo(v.x) * ev[k]     + bfhi(v.x) * ev[k + 1]
             + bflo(v.y) * ev[k + 2] + bfhi(v.y) * ev[k + 3]
             + bflo(v.z) * ev[k + 4] + bfhi(v.z) * ev[k + 5]
             + bflo(v.w) * ev[k + 6] + bfhi(v.w) * ev[k + 7];
    }
    atomicAdd(&agg[src * 48 + lane], acc);
}

// ================= fused node GRU: GEMM (S in LDS) + gates =================
// 16 nodes/block, 192 threads. asum via per-block sorted-agi reduction.
__global__ __launch_bounds__(192) void node_fused_k(const float* __restrict__ agg,
                                                    const float* __restrict__ a_in,
                                                    const float* __restrict__ wtn,
                                                    const float* __restrict__ wtun,
                                                    const float* __restrict__ bn_in,
                                                    const float* __restrict__ bn_rec,
                                                    const int* __restrict__ agi,
                                                    float* __restrict__ a_out,
                                                    float* __restrict__ asum)
{
    __shared__ float xs[16][48];
    __shared__ float hs[16][32];
    __shared__ float S[16][192];
    __shared__ int garr[16];
    int t = threadIdx.x;
    int n0 = blockIdx.x * 16;

    reinterpret_cast<float4*>(&xs[0][0])[t] =
        reinterpret_cast<const float4*>(agg + (size_t)n0 * 48)[t];       // 192 float4
    if (t < 128) reinterpret_cast<float4*>(&hs[0][0])[t] =
        reinterpret_cast<const float4*>(a_in + (size_t)n0 * 32)[t];
    if (t >= 128 && t < 144) garr[t - 128] = agi[n0 + (t - 128)];
    __syncthreads();

    if (t < 96) {
        float w[48];
        const float4* wp4 = reinterpret_cast<const float4*>(wtn + t * 48);
        #pragma unroll
        for (int q = 0; q < 12; ++q) {
            float4 v = wp4[q];
            w[4*q] = v.x; w[4*q+1] = v.y; w[4*q+2] = v.z; w[4*q+3] = v.w;
        }
        float b = bn_in[t];
        #pragma unroll 4
        for (int i = 0; i < 16; ++i) {
            float sres = b;
            #pragma unroll
            for (int k = 0; k < 48; ++k) sres += xs[i][k] * w[k];
            S[i][t] = sres;
        }
    } else {
        float w[32];
        const float4* wp4 = reinterpret_cast<const float4*>(wtun + (t - 96) * 32);
        #pragma unroll
        for (int q = 0; q < 8; ++q) {
            float4 v = wp4[q];
            w[4*q] = v.x; w[4*q+1] = v.y; w[4*q+2] = v.z; w[4*q+3] = v.w;
        }
        float b = bn_rec[t - 96];
        #pragma unroll 4
        for (int i = 0; i < 16; ++i) {
            float sres = b;
            #pragma unroll
            for (int k = 0; k < 32; ++k) sres += hs[i][k] * w[k];
            S[i][t] = sres;
        }
    }
    __syncthreads();

    for (int idx = t; idx < 512; idx += 192) {
        int le = idx >> 5, cc = idx & 31;
        int n = n0 + le;
        float z  = 1.f / (1.f + expf(-(S[le][cc] + S[le][96 + cc])));
        float r  = 1.f / (1.f + expf(-(S[le][32 + cc] + S[le][128 + cc])));
        float hc = tanhf(S[le][64 + cc] + r * S[le][160 + cc]);
        float h  = hs[le][cc];
        float val = z * h + (1.f - z) * hc;
        a_out[(size_t)n * 32 + cc] = val;
        hs[le][cc] = val;                       // stash for block-level asum reduction
    }
    __syncthreads();

    if (t < 32) {
        int cc = t;
        int gprev = garr[0];
        float run = 0.f;
        #pragma unroll 4
        for (int le = 0; le < 16; ++le) {
            int gcur = garr[le];                // wave-uniform
            if (gcur != gprev) {
                atomicAdd(&asum[gprev * 32 + cc], run);
                run = 0.f; gprev = gcur;
            }
            run += hs[le][cc];
        }
        atomicAdd(&asum[gprev * 32 + cc], run);
    }
}

// ================= state GRU =================
__global__ void state_gru_k(const float* __restrict__ asum, const float* __restrict__ esum,
                            const float* __restrict__ s_in,
                            const float* __restrict__ Ws, const float* __restrict__ Us,
                            const float* __restrict__ bs_in, const float* __restrict__ bs_rec,
                            float* __restrict__ s_out)
{
    __shared__ float xs[80];
    __shared__ float hsv[16];
    __shared__ float S[48];
    __shared__ float Uh[16];
    int g = blockIdx.x;
    int t = threadIdx.x;
    if (t < 80) {
        float v;
        if (t < 32)      v = asum[g * 32 + t];
        else if (t < 64) v = esum[g * 32 + (t - 32)];
        else             v = s_in[g * 16 + (t - 64)];
        xs[t] = v;
        if (t >= 64) hsv[t - 64] = v;
    }
    __syncthreads();
    if (t < 48) {
        float gacc = bs_in[t];
        #pragma unroll
        for (int k = 0; k < 80; ++k) gacc += xs[k] * Ws[k * 48 + t];
        float u = bs_rec[t];
        #pragma unroll
        for (int k = 0; k < 16; ++k) u += hsv[k] * Us[k * 48 + t];
        if (t < 32) { S[t] = gacc + u; }
        else        { S[t] = gacc; Uh[t - 32] = u; }
    }
    __syncthreads();
    if (t < 16) {
        float z  = 1.f / (1.f + expf(-S[t]));
        float r  = 1.f / (1.f + expf(-S[16 + t]));
        float hc = tanhf(S[32 + t] + r * Uh[t]);
        s_out[g * 16 + t] = z * hsv[t] + (1.f - z) * hc;
    }
}

extern "C" void kernel_launch(void* const* d_in, const int* in_sizes, int n_in,
                              void* d_out, int out_size, void* d_ws, size_t ws_size,
                              hipStream_t stream)
{
    const float* a0      = (const float*)d_in[0];
    const float* e0      = (const float*)d_in[1];
    const float* s0      = (const float*)d_in[2];
    const int*   pair    = (const int*)d_in[3];
    const int*   agi     = (const int*)d_in[4];
    const int*   bgi     = (const int*)d_in[5];
    const float* kernelw = (const float*)d_in[6];
    const float* bias    = (const float*)d_in[7];
    const float* We      = (const float*)d_in[8];
    const float* Ue      = (const float*)d_in[9];
    const float* be_in   = (const float*)d_in[10];
    const float* be_rec  = (const float*)d_in[11];
    const float* Wn      = (const float*)d_in[12];
    const float* Un      = (const float*)d_in[13];
    const float* bn_in   = (const float*)d_in[14];
    const float* bn_rec  = (const float*)d_in[15];
    const float* Ws      = (const float*)d_in[16];
    const float* Us      = (const float*)d_in[17];
    const float* bs_in   = (const float*)d_in[18];
    const float* bs_rec  = (const float*)d_in[19];

    float* out_a = (float*)d_out;                    // N*32
    float* out_e = out_a + N_ATOMS * 32;             // E*32
    float* out_s = out_e + (size_t)N_EDGES * 32;     // G*16

    char* wp = (char*)d_ws;
    auto alloc = [&](size_t nf) { float* p = (float*)wp; wp += nf * sizeof(float); return p; };
    float* aW   = alloc((size_t)N_ATOMS * 32);
    float* eW   = alloc((size_t)N_EDGES * 32);
    float* sW   = alloc((size_t)N_GRAPH * 16);
    ushort_t* Yb = (ushort_t*)alloc((size_t)N_ATOMS * 1536 / 2);  // bf16, 30.7 MB
    float* Bn   = alloc((size_t)N_ATOMS * 48);
    float* agg  = alloc((size_t)N_ATOMS * 48);       // agg..esum contiguous memset
    float* asum = alloc((size_t)N_GRAPH * 32);
    float* esum = alloc((size_t)N_GRAPH * 32);
    float* PA   = alloc((size_t)N_ATOMS * 192);
    float* PS   = alloc((size_t)N_GRAPH * 96);
    float* wta  = alloc(6144);
    float* wts  = alloc(1536);
    float* wtee = alloc(6144);
    float* wtn  = alloc(4608);
    float* wtun = alloc(3072);
    ushort_t* kb = (ushort_t*)alloc(36864);          // 73728 bf16 = kernel(32x2304)
    size_t zero_bytes = ((size_t)N_ATOMS * 48 + 2 * N_GRAPH * 32) * sizeof(float);

    trans_k<<<372, 256, 0, stream>>>(We, Ue, Wn, Un, kernelw,
                                     wta, wts, wtee, wtn, wtun, kb);

    const float* a_in = a0;
    const float* e_in = e0;
    const float* s_in = s0;

    for (int step = 0; step < 2; ++step) {
        float* a_o = (step == 0) ? aW : out_a;
        float* e_o = (step == 0) ? eW : out_e;
        float* s_o = (step == 0) ? sW : out_s;

        hipMemsetAsync(agg, 0, zero_bytes, stream);
        pa_k<<<N_ATOMS / 16, 192, 0, stream>>>(a_in, wta, PA);
        ps_k<<<N_GRAPH / 16, 96, 0, stream>>>(s_in, wts, be_in, PS);
        edge_fused_k<<<N_EDGES / 16, 192, 0, stream>>>(e_in, wtee, be_rec, PA, PS,
                                                       pair, bgi, e_o, esum);
        y_mfma_k<<<(N_ATOMS + 31) / 32, 256, 0, stream>>>(kb, bias, a_in, s_in, agi, Yb, Bn);
        edge_msg_k<<<N_EDGES / 4, 256, 0, stream>>>(e_o, pair, Yb, Bn, agg);
        node_fused_k<<<N_ATOMS / 16, 192, 0, stream>>>(agg, a_in, wtn, wtun,
                                                       bn_in, bn_rec, agi, a_o, asum);
        state_gru_k<<<N_GRAPH, 128, 0, stream>>>(asum, esum, s_in, Ws, Us, bs_in, bs_rec, s_o);

        a_in = a_o; e_in = e_o; s_in = s_o;
    }
}